// Round 5
// baseline (417.740 us; speedup 1.0000x reference)
//
#include <hip/hip_runtime.h>

// Problem constants
#define NH 16
#define HD 64
#define CE 1024
#define TT 2048
#define BB 4
#define MM 8192   // B*T

using bf16x8 = __attribute__((ext_vector_type(8))) __bf16;
using f32x4  = __attribute__((ext_vector_type(4))) float;

__device__ __forceinline__ unsigned short f2bf(float f) {
  unsigned int u = __float_as_uint(f);
  u += 0x7fffu + ((u >> 16) & 1u);   // RNE
  return (unsigned short)(u >> 16);
}
__device__ __forceinline__ unsigned short f2bf_rtz(float f) {
  return (unsigned short)(__float_as_uint(f) >> 16);  // truncate: 1-op, used for P only
}

// async global->LDS, 16B per lane; LDS dst must be wave-uniform (HW adds lane*16)
__device__ __forceinline__ void async_cp16(const unsigned short* g, unsigned short* l) {
  __builtin_amdgcn_global_load_lds(
      (const __attribute__((address_space(1))) unsigned int*)g,
      (__attribute__((address_space(3))) unsigned int*)l, 16, 0, 0);
}

// ---------------- fp32 -> bf16 convert (x) ----------------
__global__ __launch_bounds__(256) void convert_x(const float* __restrict__ in,
                                                 unsigned short* __restrict__ out) {
  const int i = (blockIdx.x * 256 + threadIdx.x) * 4;
  const float4 v = *(const float4*)(in + i);
  ushort4 o;
  o.x = f2bf(v.x); o.y = f2bf(v.y); o.z = f2bf(v.z); o.w = f2bf(v.w);
  *(ushort4*)(out + i) = o;
}

// ------------- transpose + fp32->bf16: in[rows][cols] f32 -> out[cols][rows] bf16 -------------
__global__ __launch_bounds__(256) void transpose_conv(const float* __restrict__ in,
                                                      unsigned short* __restrict__ out,
                                                      int rows, int cols) {
  __shared__ unsigned short tile[32][33];
  int c0 = blockIdx.x * 32, r0 = blockIdx.y * 32;
  int tx = threadIdx.x & 31, ty = threadIdx.x >> 5;  // ty 0..7
#pragma unroll
  for (int i = ty; i < 32; i += 8)
    tile[i][tx] = f2bf(in[(size_t)(r0 + i) * cols + c0 + tx]);
  __syncthreads();
#pragma unroll
  for (int i = ty; i < 32; i += 8)
    out[(size_t)(c0 + i) * rows + r0 + tx] = tile[tx][i];
}

// ------------- per-head V transpose (bf16): in[bh][2048][64] -> out[bh][64][2048] -------------
__global__ __launch_bounds__(256) void transpose_v(const unsigned short* __restrict__ in,
                                                   unsigned short* __restrict__ out) {
  __shared__ unsigned short tile[32][33];
  const int bh = blockIdx.z;
  const int t0 = blockIdx.y * 32, d0 = blockIdx.x * 32;
  const int tx = threadIdx.x & 31, ty = threadIdx.x >> 5;
  const size_t base = (size_t)bh * TT * HD;
#pragma unroll
  for (int i = ty; i < 32; i += 8)
    tile[i][tx] = in[base + (size_t)(t0 + i) * HD + d0 + tx];
  __syncthreads();
#pragma unroll
  for (int i = ty; i < 32; i += 8)
    out[base + (size_t)(d0 + i) * TT + t0 + tx] = tile[tx][i];
}

// ---------------- GEMM core (m97 structure): C[128x128] tile of A[M,1024] @ BT[N,1024]^T --------
__device__ __forceinline__ void gemm_core(const unsigned short* __restrict__ A,
                                          const unsigned short* __restrict__ BT,
                                          int m0, int n0, f32x4 (&acc)[4][4]) {
  __shared__ unsigned short As[128 * 32];
  __shared__ unsigned short Bs[128 * 32];
  const int tid  = threadIdx.x;
  const int lane = tid & 63;
  const int wave = tid >> 6;
  const int quad = lane >> 4;
  const int l15  = lane & 15;
  const int wm = (wave & 1) * 64;
  const int wn = (wave >> 1) * 64;
  const int ldr = tid >> 2;         // 0..63
  const int ldc = (tid & 3) * 8;    // 0,8,16,24
  const unsigned short* Ap = A + (size_t)(m0 + ldr) * CE + ldc;
  const unsigned short* Bp = BT + (size_t)(n0 + ldr) * CE + ldc;
  unsigned short* AsW0 = As + wave * 512;          // wave-uniform LDS dst, rows 0..63
  unsigned short* AsW1 = As + 2048 + wave * 512;   // rows 64..127
  unsigned short* BsW0 = Bs + wave * 512;
  unsigned short* BsW1 = Bs + 2048 + wave * 512;
  for (int k0 = 0; k0 < CE; k0 += 32) {
    async_cp16(Ap + k0, AsW0);
    async_cp16(Ap + (size_t)64 * CE + k0, AsW1);
    async_cp16(Bp + k0, BsW0);
    async_cp16(Bp + (size_t)64 * CE + k0, BsW1);
    __syncthreads();   // compiler emits vmcnt(0) drain before barrier
    bf16x8 af[4], bfr[4];
#pragma unroll
    for (int i = 0; i < 4; i++) {
      af[i]  = *(const bf16x8*)&As[(wm + i * 16 + l15) * 32 + quad * 8];
      bfr[i] = *(const bf16x8*)&Bs[(wn + i * 16 + l15) * 32 + quad * 8];
    }
#pragma unroll
    for (int mi = 0; mi < 4; mi++)
#pragma unroll
      for (int ni = 0; ni < 4; ni++)
        acc[mi][ni] = __builtin_amdgcn_mfma_f32_16x16x32_bf16(af[mi], bfr[ni], acc[mi][ni], 0, 0, 0);
    __syncthreads();
  }
}

// ---------------- GEMM 1: qkv = x @ w_qkv, scattered into Q (scaled), K, V (coalesced) ---------
// Q pre-scaled by HD^-0.5 * log2(e): flash computes exp2(s) == exp(s / log2e) exactly.
__global__ __launch_bounds__(256) void gemm_qkv(const unsigned short* __restrict__ A,
                                                const unsigned short* __restrict__ BT,
                                                unsigned short* __restrict__ Qb,
                                                unsigned short* __restrict__ Kb,
                                                unsigned short* __restrict__ Vb) {
  f32x4 acc[4][4] = {};
  const int m0 = blockIdx.y * 128, n0 = blockIdx.x * 128;
  gemm_core(A, BT, m0, n0, acc);
  const int tid = threadIdx.x, lane = tid & 63, wave = tid >> 6;
  const int quad = lane >> 4, l15 = lane & 15;
  const int wm = (wave & 1) * 64, wn = (wave >> 1) * 64;
  const float QSCALE = 0.125f * 1.44269504088896340736f;
#pragma unroll
  for (int mi = 0; mi < 4; mi++) {
#pragma unroll
    for (int ni = 0; ni < 4; ni++) {
      const int n = n0 + wn + ni * 16 + l15;
      const int s = n >> 10;           // 0=q 1=k 2=v
      const int h = (n >> 6) & 15;
      const int d = n & 63;
#pragma unroll
      for (int r = 0; r < 4; r++) {
        const int m = m0 + wm + mi * 16 + quad * 4 + r;
        const int b = m >> 11;         // /2048
        const int t = m & 2047;
        const int bh = (b << 4) + h;
        const float v = acc[mi][ni][r];
        if (s == 0)      Qb[((size_t)bh * TT + t) * HD + d] = f2bf(v * QSCALE);
        else if (s == 1) Kb[((size_t)bh * TT + t) * HD + d] = f2bf(v);
        else             Vb[((size_t)bh * TT + t) * HD + d] = f2bf(v);
      }
    }
  }
}

// ---------------- GEMM 2: out = AO @ w_out + b_out (fp32 out) ----------------
__global__ __launch_bounds__(256) void gemm_out(const unsigned short* __restrict__ A,
                                                const unsigned short* __restrict__ BT,
                                                const float* __restrict__ bias,
                                                float* __restrict__ out) {
  f32x4 acc[4][4] = {};
  const int m0 = blockIdx.y * 128, n0 = blockIdx.x * 128;
  gemm_core(A, BT, m0, n0, acc);
  const int tid = threadIdx.x, lane = tid & 63, wave = tid >> 6;
  const int quad = lane >> 4, l15 = lane & 15;
  const int wm = (wave & 1) * 64, wn = (wave >> 1) * 64;
#pragma unroll
  for (int mi = 0; mi < 4; mi++) {
#pragma unroll
    for (int ni = 0; ni < 4; ni++) {
      const int n = n0 + wn + ni * 16 + l15;
      const float bv = bias[n];
#pragma unroll
      for (int r = 0; r < 4; r++) {
        const int m = m0 + wm + mi * 16 + quad * 4 + r;
        out[(size_t)m * CE + n] = acc[mi][ni][r] + bv;
      }
    }
  }
}

// ---------------- causal flash attention: 4-wave blocks, 64-row Q tiles, XCD-swizzled ----------
// Block = 256 thr / 4 waves; wave owns 16 Q rows. KV tile 64 staged in padded LDS via
// one-iteration-ahead register prefetch (issued BEFORE the barrier). Grid (16, B*H) = 1024
// blocks -> 4 blocks/CU resident (16 waves/CU), twice round-4's latency hiding. The doubled
// per-block KV stream is absorbed by L2 thanks to the T1 XCD-chunked swizzle (verified round 4:
// FETCH 152->24.6 MB): XCD c holds heads [8c,8c+8), KV working set 4MB = L2 size.
// Block pairs q-tiles pt and 31-pt -> 33 KV iters every block, perfectly balanced.
// T5 setprio around MFMA clusters. Fixed-reference softmax (Q pre-scaled by log2e).
__global__ __launch_bounds__(256) void flash_attn(const unsigned short* __restrict__ Q,
                                                  const unsigned short* __restrict__ Kg,
                                                  const unsigned short* __restrict__ Vt,
                                                  unsigned short* __restrict__ AO) {
  __shared__ unsigned short Ks[64][72];     // [kv][d]
  __shared__ unsigned short Vs[64][72];     // [d][kv]
  __shared__ unsigned short Ps[4][16][72];  // per-wave P, [qrow 0..15][kv]
  // T1 chunked swizzle: hw assigns flat%8 -> XCD; XCD c gets wu in [128c,128c+128)
  const int flat = blockIdx.x + 16 * blockIdx.y;       // 0..1023, hw dispatch order
  const int wu   = (flat & 7) * 128 + (flat >> 3);     // bijective remap
  const int qx   = wu & 15;                            // q-tile index 0..15
  const int bh   = wu >> 4;                            // head 0..63 (8 consecutive heads/XCD)
  const int tid = threadIdx.x, w = tid >> 6, lane = tid & 63;
  const int quad = lane >> 4, l15 = lane & 15;
  const int b = bh >> 4, h = bh & 15;
  const unsigned short* Kbase = Kg + (size_t)bh * TT * HD;
  const unsigned short* Vbase = Vt + (size_t)bh * HD * TT;
  const int srow = tid >> 2;        // 0..63
  const int scol = (tid & 3) * 16;  // 0,16,32,48
  const bf16x8 ones = {1, 1, 1, 1, 1, 1, 1, 1};

  for (int ph = 0; ph < 2; ph++) {
    const int pt = ph ? (31 - qx) : qx;
    const int q0 = pt * 64;
    const int n_it = pt + 1;
    const int rbase = q0 + w * 16;    // this wave's first Q row
    // Q fragment: 1 m-frag per wave; A[m=l15][k=quad*8+j (+32)]
    bf16x8 qf[2];
    {
      const unsigned short* Qp =
          Q + ((size_t)bh * TT + rbase + l15) * HD + quad * 8;
      qf[0] = *(const bf16x8*)Qp;
      qf[1] = *(const bf16x8*)(Qp + 32);
    }
    f32x4 o[4] = {};
    f32x4 l_acc = {};
    // initial prefetch (tile 0 of this phase)
    uint4 kreg[2], vreg[2];
    {
      const unsigned short* kp = Kbase + (size_t)srow * HD + scol;
      kreg[0] = *(const uint4*)kp;
      kreg[1] = *(const uint4*)(kp + 8);
      const unsigned short* vp = Vbase + (size_t)srow * TT + scol;
      vreg[0] = *(const uint4*)vp;
      vreg[1] = *(const uint4*)(vp + 8);
    }
    for (int it = 0; it < n_it; it++) {
      const int kv0 = it * 64;
      // commit prefetched tile to LDS
      *(uint4*)&Ks[srow][scol]     = kreg[0];
      *(uint4*)&Ks[srow][scol + 8] = kreg[1];
      *(uint4*)&Vs[srow][scol]     = vreg[0];
      *(uint4*)&Vs[srow][scol + 8] = vreg[1];
      // issue next tile's loads BEFORE the barrier; they fly across it and during compute
      {
        const int itn = (it + 1 < n_it) ? it + 1 : it;
        const int kvn = itn * 64;
        const unsigned short* kp = Kbase + (size_t)(kvn + srow) * HD + scol;
        kreg[0] = *(const uint4*)kp;
        kreg[1] = *(const uint4*)(kp + 8);
        const unsigned short* vp = Vbase + (size_t)srow * TT + kvn + scol;
        vreg[0] = *(const uint4*)vp;
        vreg[1] = *(const uint4*)(vp + 8);
      }
      __syncthreads();
      // waves fully above this KV tile produce all-zero P: skip (wave-uniform)
      if (kv0 <= rbase + 15) {
        // K fragments
        bf16x8 kb[4][2];
#pragma unroll
        for (int ni = 0; ni < 4; ni++) {
          kb[ni][0] = *(const bf16x8*)&Ks[ni * 16 + l15][quad * 8];
          kb[ni][1] = *(const bf16x8*)&Ks[ni * 16 + l15][32 + quad * 8];
        }
        // S = Q K^T
        f32x4 s[4];
        __builtin_amdgcn_s_setprio(1);
#pragma unroll
        for (int ni = 0; ni < 4; ni++) {
          f32x4 z = {};
          z = __builtin_amdgcn_mfma_f32_16x16x32_bf16(qf[0], kb[ni][0], z, 0, 0, 0);
          z = __builtin_amdgcn_mfma_f32_16x16x32_bf16(qf[1], kb[ni][1], z, 0, 0, 0);
          s[ni] = z;
        }
        __builtin_amdgcn_s_setprio(0);
        // V fragments (independent of P: their lgkm waits overlap the exp chain below)
        bf16x8 vb[4][2];
#pragma unroll
        for (int nd = 0; nd < 4; nd++) {
          vb[nd][0] = *(const bf16x8*)&Vs[nd * 16 + l15][quad * 8];
          vb[nd][1] = *(const bf16x8*)&Vs[nd * 16 + l15][32 + quad * 8];
        }
        // P = exp2(S); mask only when the diagonal touches this wave (wave-uniform branch)
        if (kv0 + 63 > rbase) {
#pragma unroll
          for (int ni = 0; ni < 4; ni++) {
            const int col_g = kv0 + ni * 16 + l15;
#pragma unroll
            for (int r = 0; r < 4; r++) {
              const int row_g = rbase + quad * 4 + r;
              const float sv = (col_g <= row_g) ? s[ni][r] : -1e30f;
              Ps[w][quad * 4 + r][ni * 16 + l15] = f2bf_rtz(exp2f(sv));
            }
          }
        } else {
#pragma unroll
          for (int ni = 0; ni < 4; ni++)
#pragma unroll
            for (int r = 0; r < 4; r++)
              Ps[w][quad * 4 + r][ni * 16 + l15] = f2bf_rtz(exp2f(s[ni][r]));
        }
        // per-wave LDS round-trip: C-layout -> A-layout (intra-wave, lgkmcnt-ordered)
        bf16x8 pa[2];
        pa[0] = *(const bf16x8*)&Ps[w][l15][quad * 8];
        pa[1] = *(const bf16x8*)&Ps[w][l15][32 + quad * 8];
        // l += row-sum(P) via ones-B MFMA; O += P @ V
        __builtin_amdgcn_s_setprio(1);
        l_acc = __builtin_amdgcn_mfma_f32_16x16x32_bf16(pa[0], ones, l_acc, 0, 0, 0);
        l_acc = __builtin_amdgcn_mfma_f32_16x16x32_bf16(pa[1], ones, l_acc, 0, 0, 0);
#pragma unroll
        for (int nd = 0; nd < 4; nd++) {
          o[nd] = __builtin_amdgcn_mfma_f32_16x16x32_bf16(pa[0], vb[nd][0], o[nd], 0, 0, 0);
          o[nd] = __builtin_amdgcn_mfma_f32_16x16x32_bf16(pa[1], vb[nd][1], o[nd], 0, 0, 0);
        }
        __builtin_amdgcn_s_setprio(0);
      }
      __syncthreads();  // LDS reads done before next iteration's commit
    }
    // epilogue: normalize and write [B,T,H*D]
    {
      float rin[4];
#pragma unroll
      for (int r = 0; r < 4; r++) rin[r] = __builtin_amdgcn_rcpf(l_acc[r]);
#pragma unroll
      for (int nd = 0; nd < 4; nd++)
#pragma unroll
        for (int r = 0; r < 4; r++) {
          const int row_g = rbase + quad * 4 + r;
          const size_t mg = (size_t)b * TT + row_g;
          AO[mg * CE + h * 64 + nd * 16 + l15] = f2bf(o[nd][r] * rin[r]);
        }
    }
  }
}

extern "C" void kernel_launch(void* const* d_in, const int* in_sizes, int n_in,
                              void* d_out, int out_size, void* d_ws, size_t ws_size,
                              hipStream_t stream) {
  const float* x     = (const float*)d_in[0];  // [4,2048,1024] f32
  const float* w_qkv = (const float*)d_in[1];  // [1024,3072] f32
  const float* w_out = (const float*)d_in[2];  // [1024,1024] f32
  const float* b_out = (const float*)d_in[3];  // [1024] f32
  float* out = (float*)d_out;                  // [4,2048,1024] f32

  unsigned short* ws  = (unsigned short*)d_ws;
  unsigned short* Xb  = ws;                                  // x bf16 [8192][1024]
  unsigned short* Wt1 = Xb  + (size_t)MM * CE;               // w_qkv^T  [3072][1024]
  unsigned short* Wt2 = Wt1 + (size_t)3072 * 1024;           // w_out^T  [1024][1024]
  unsigned short* Qb  = Wt2 + (size_t)1024 * 1024;           // [BH][T][64]
  unsigned short* Kb  = Qb  + (size_t)8388608;               // [BH][T][64]
  unsigned short* Vb  = Kb  + (size_t)8388608;               // [BH][T][64]
  unsigned short* Vtb = Vb  + (size_t)8388608;               // [BH][64][T]
  unsigned short* AO  = Vtb + (size_t)8388608;               // [M][1024] bf16

  convert_x     <<<dim3(8192), 256, 0, stream>>>(x, Xb);
  transpose_conv<<<dim3(96, 32), 256, 0, stream>>>(w_qkv, Wt1, 1024, 3072);
  transpose_conv<<<dim3(32, 32), 256, 0, stream>>>(w_out, Wt2, 1024, 1024);
  gemm_qkv  <<<dim3(24, 64), 256, 0, stream>>>(Xb, Wt1, Qb, Kb, Vb);
  transpose_v<<<dim3(2, 64, 64), 256, 0, stream>>>(Vb, Vtb);
  flash_attn<<<dim3(16, 64), 256, 0, stream>>>(Qb, Kb, Vtb, AO);
  gemm_out  <<<dim3(8, 64), 256, 0, stream>>>(AO, Wt2, b_out, out);
}

// Round 6
// 331.380 us; speedup vs baseline: 1.2606x; 1.2606x over previous
//
#include <hip/hip_runtime.h>

// Problem constants
#define NH 16
#define HD 64
#define CE 1024
#define TT 2048
#define BB 4
#define MM 8192   // B*T

using bf16x8 = __attribute__((ext_vector_type(8))) __bf16;
using f32x4  = __attribute__((ext_vector_type(4))) float;

__device__ __forceinline__ unsigned short f2bf(float f) {
  unsigned int u = __float_as_uint(f);
  u += 0x7fffu + ((u >> 16) & 1u);   // RNE
  return (unsigned short)(u >> 16);
}
__device__ __forceinline__ unsigned short f2bf_rtz(float f) {
  return (unsigned short)(__float_as_uint(f) >> 16);  // truncate: 1-op, used for P only
}

// async global->LDS, 16B per lane; LDS dst must be wave-uniform (HW adds lane*16)
__device__ __forceinline__ void async_cp16(const unsigned short* g, unsigned short* l) {
  __builtin_amdgcn_global_load_lds(
      (const __attribute__((address_space(1))) unsigned int*)g,
      (__attribute__((address_space(3))) unsigned int*)l, 16, 0, 0);
}

// ---------------- fp32 -> bf16 convert (x) ----------------
__global__ __launch_bounds__(256) void convert_x(const float* __restrict__ in,
                                                 unsigned short* __restrict__ out) {
  const int i = (blockIdx.x * 256 + threadIdx.x) * 4;
  const float4 v = *(const float4*)(in + i);
  ushort4 o;
  o.x = f2bf(v.x); o.y = f2bf(v.y); o.z = f2bf(v.z); o.w = f2bf(v.w);
  *(ushort4*)(out + i) = o;
}

// ------------- transpose + fp32->bf16: in[rows][cols] f32 -> out[cols][rows] bf16 -------------
__global__ __launch_bounds__(256) void transpose_conv(const float* __restrict__ in,
                                                      unsigned short* __restrict__ out,
                                                      int rows, int cols) {
  __shared__ unsigned short tile[32][33];
  int c0 = blockIdx.x * 32, r0 = blockIdx.y * 32;
  int tx = threadIdx.x & 31, ty = threadIdx.x >> 5;  // ty 0..7
#pragma unroll
  for (int i = ty; i < 32; i += 8)
    tile[i][tx] = f2bf(in[(size_t)(r0 + i) * cols + c0 + tx]);
  __syncthreads();
#pragma unroll
  for (int i = ty; i < 32; i += 8)
    out[(size_t)(c0 + i) * rows + r0 + tx] = tile[tx][i];
}

// ------------- per-head V transpose (bf16): in[bh][2048][64] -> out[bh][64][2048] -------------
__global__ __launch_bounds__(256) void transpose_v(const unsigned short* __restrict__ in,
                                                   unsigned short* __restrict__ out) {
  __shared__ unsigned short tile[32][33];
  const int bh = blockIdx.z;
  const int t0 = blockIdx.y * 32, d0 = blockIdx.x * 32;
  const int tx = threadIdx.x & 31, ty = threadIdx.x >> 5;
  const size_t base = (size_t)bh * TT * HD;
#pragma unroll
  for (int i = ty; i < 32; i += 8)
    tile[i][tx] = in[base + (size_t)(t0 + i) * HD + d0 + tx];
  __syncthreads();
#pragma unroll
  for (int i = ty; i < 32; i += 8)
    out[base + (size_t)(d0 + i) * TT + t0 + tx] = tile[tx][i];
}

// ---------------- GEMM core (m97 structure): C[128x128] tile of A[M,1024] @ BT[N,1024]^T --------
__device__ __forceinline__ void gemm_core(const unsigned short* __restrict__ A,
                                          const unsigned short* __restrict__ BT,
                                          int m0, int n0, f32x4 (&acc)[4][4]) {
  __shared__ unsigned short As[128 * 32];
  __shared__ unsigned short Bs[128 * 32];
  const int tid  = threadIdx.x;
  const int lane = tid & 63;
  const int wave = tid >> 6;
  const int quad = lane >> 4;
  const int l15  = lane & 15;
  const int wm = (wave & 1) * 64;
  const int wn = (wave >> 1) * 64;
  const int ldr = tid >> 2;         // 0..63
  const int ldc = (tid & 3) * 8;    // 0,8,16,24
  const unsigned short* Ap = A + (size_t)(m0 + ldr) * CE + ldc;
  const unsigned short* Bp = BT + (size_t)(n0 + ldr) * CE + ldc;
  unsigned short* AsW0 = As + wave * 512;          // wave-uniform LDS dst, rows 0..63
  unsigned short* AsW1 = As + 2048 + wave * 512;   // rows 64..127
  unsigned short* BsW0 = Bs + wave * 512;
  unsigned short* BsW1 = Bs + 2048 + wave * 512;
  for (int k0 = 0; k0 < CE; k0 += 32) {
    async_cp16(Ap + k0, AsW0);
    async_cp16(Ap + (size_t)64 * CE + k0, AsW1);
    async_cp16(Bp + k0, BsW0);
    async_cp16(Bp + (size_t)64 * CE + k0, BsW1);
    __syncthreads();   // compiler emits vmcnt(0) drain before barrier
    bf16x8 af[4], bfr[4];
#pragma unroll
    for (int i = 0; i < 4; i++) {
      af[i]  = *(const bf16x8*)&As[(wm + i * 16 + l15) * 32 + quad * 8];
      bfr[i] = *(const bf16x8*)&Bs[(wn + i * 16 + l15) * 32 + quad * 8];
    }
#pragma unroll
    for (int mi = 0; mi < 4; mi++)
#pragma unroll
      for (int ni = 0; ni < 4; ni++)
        acc[mi][ni] = __builtin_amdgcn_mfma_f32_16x16x32_bf16(af[mi], bfr[ni], acc[mi][ni], 0, 0, 0);
    __syncthreads();
  }
}

// ---------------- GEMM 1: qkv = x @ w_qkv, scattered into Q (scaled), K, V (coalesced) ---------
// Q pre-scaled by HD^-0.5 * log2(e): flash computes exp2(s) == exp(s / log2e) exactly.
__global__ __launch_bounds__(256) void gemm_qkv(const unsigned short* __restrict__ A,
                                                const unsigned short* __restrict__ BT,
                                                unsigned short* __restrict__ Qb,
                                                unsigned short* __restrict__ Kb,
                                                unsigned short* __restrict__ Vb) {
  f32x4 acc[4][4] = {};
  const int m0 = blockIdx.y * 128, n0 = blockIdx.x * 128;
  gemm_core(A, BT, m0, n0, acc);
  const int tid = threadIdx.x, lane = tid & 63, wave = tid >> 6;
  const int quad = lane >> 4, l15 = lane & 15;
  const int wm = (wave & 1) * 64, wn = (wave >> 1) * 64;
  const float QSCALE = 0.125f * 1.44269504088896340736f;
#pragma unroll
  for (int mi = 0; mi < 4; mi++) {
#pragma unroll
    for (int ni = 0; ni < 4; ni++) {
      const int n = n0 + wn + ni * 16 + l15;
      const int s = n >> 10;           // 0=q 1=k 2=v
      const int h = (n >> 6) & 15;
      const int d = n & 63;
#pragma unroll
      for (int r = 0; r < 4; r++) {
        const int m = m0 + wm + mi * 16 + quad * 4 + r;
        const int b = m >> 11;         // /2048
        const int t = m & 2047;
        const int bh = (b << 4) + h;
        const float v = acc[mi][ni][r];
        if (s == 0)      Qb[((size_t)bh * TT + t) * HD + d] = f2bf(v * QSCALE);
        else if (s == 1) Kb[((size_t)bh * TT + t) * HD + d] = f2bf(v);
        else             Vb[((size_t)bh * TT + t) * HD + d] = f2bf(v);
      }
    }
  }
}

// ---------------- GEMM 2: out = AO @ w_out + b_out (fp32 out) ----------------
__global__ __launch_bounds__(256) void gemm_out(const unsigned short* __restrict__ A,
                                                const unsigned short* __restrict__ BT,
                                                const float* __restrict__ bias,
                                                float* __restrict__ out) {
  f32x4 acc[4][4] = {};
  const int m0 = blockIdx.y * 128, n0 = blockIdx.x * 128;
  gemm_core(A, BT, m0, n0, acc);
  const int tid = threadIdx.x, lane = tid & 63, wave = tid >> 6;
  const int quad = lane >> 4, l15 = lane & 15;
  const int wm = (wave & 1) * 64, wn = (wave >> 1) * 64;
#pragma unroll
  for (int mi = 0; mi < 4; mi++) {
#pragma unroll
    for (int ni = 0; ni < 4; ni++) {
      const int n = n0 + wn + ni * 16 + l15;
      const float bv = bias[n];
#pragma unroll
      for (int r = 0; r < 4; r++) {
        const int m = m0 + wm + mi * 16 + quad * 4 + r;
        out[(size_t)m * CE + n] = acc[mi][ni][r] + bv;
      }
    }
  }
}

// ---------------- causal flash attention: 8-wave blocks, 128-row Q tiles, K-direct -------------
// Base = round-4 verified kernel (512 thr / 8 waves, 128-row tiles, T1 XCD swizzle, T5 setprio).
// Changes (theory: LDS-pipe-bound at ~2688 cyc/blk-iter):
//  1. K fragments load DIRECT from L2 (per-lane dwordx4, prefetched one iter ahead into the same
//     registers) - no K LDS staging/reads at all (saves 72 of 160 b128 LDS ops per blk-iter).
//  2. LDS pad 72 -> 74 (stride 37 dwords == 5 mod 32): V-frag / P-gather banks become <=2-way.
//  3. Vs double-buffered -> single barrier per iteration.
__global__ __launch_bounds__(512) void flash_attn(const unsigned short* __restrict__ Q,
                                                  const unsigned short* __restrict__ Kg,
                                                  const unsigned short* __restrict__ Vt,
                                                  unsigned short* __restrict__ AO) {
  __shared__ unsigned short Vs[2][64][74];  // [buf][d][kv], pad 74 (==5 mod 32 dword stride)
  __shared__ unsigned short Ps[8][16][74];  // per-wave P, [qrow 0..15][kv]
  // T1 chunked swizzle: hw assigns flat%8 -> XCD; XCD c gets wu in [64c,64c+64)
  const int flat = blockIdx.x + 8 * blockIdx.y;        // 0..511, hw dispatch order
  const int wu   = (flat & 7) * 64 + (flat >> 3);      // bijective remap
  const int qx   = wu & 7;                             // q-tile index 0..7
  const int bh   = wu >> 3;                            // head 0..63 (8 consecutive heads/XCD)
  const int tid = threadIdx.x, w = tid >> 6, lane = tid & 63;
  const int quad = lane >> 4, l15 = lane & 15;
  const int b = bh >> 4, h = bh & 15;
  const unsigned short* Kbase = Kg + (size_t)bh * TT * HD;
  const unsigned short* Vbase = Vt + (size_t)bh * HD * TT;
  const int srow = tid >> 3;        // 0..63
  const int scol = (tid & 7) * 8;   // 0..56 ushorts (16B chunks)
  const bf16x8 ones = {1, 1, 1, 1, 1, 1, 1, 1};

  for (int ph = 0; ph < 2; ph++) {
    const int pt = ph ? (15 - qx) : qx;
    const int q0 = pt * 128;
    const int n_it = 2 * pt + 2;
    const int rbase = q0 + w * 16;    // this wave's first Q row
    // Q fragment: 1 m-frag per wave; A[m=l15][k=quad*8+j (+32)]
    bf16x8 qf[2];
    {
      const unsigned short* Qp =
          Q + ((size_t)bh * TT + rbase + l15) * HD + quad * 8;
      qf[0] = *(const bf16x8*)Qp;
      qf[1] = *(const bf16x8*)(Qp + 32);
    }
    f32x4 o[4] = {};
    f32x4 l_acc = {};
    // per-lane K fragment base: row l15, col quad*8; add (kv0 + ni*16)*HD per frag
    const unsigned short* Kf = Kbase + (size_t)l15 * HD + quad * 8;
    // prologue: V tile 0 -> regs -> buf0; K tile 0 -> frag regs; issue V tile 1
    uint4 vreg = *(const uint4*)(Vbase + (size_t)srow * TT + scol);
    *(uint4*)&Vs[0][srow][scol] = vreg;
    bf16x8 kb[4][2];
#pragma unroll
    for (int ni = 0; ni < 4; ni++) {   // all waves active at kv0=0
      kb[ni][0] = *(const bf16x8*)(Kf + (size_t)(ni * 16) * HD);
      kb[ni][1] = *(const bf16x8*)(Kf + (size_t)(ni * 16) * HD + 32);
    }
    vreg = *(const uint4*)(Vbase + (size_t)srow * TT + (n_it > 1 ? 64 : 0) + scol);
    __syncthreads();
    for (int it = 0; it < n_it; it++) {
      const int kv0 = it * 64;
      const int cur = it & 1;
      // commit V tile it+1 into the other buffer; issue V tile it+2 (block-uniform branch)
      if (it + 1 < n_it) {
        *(uint4*)&Vs[cur ^ 1][srow][scol] = vreg;
        const int itn = (it + 2 < n_it) ? it + 2 : it + 1;
        vreg = *(const uint4*)(Vbase + (size_t)srow * TT + itn * 64 + scol);
      }
      // active iters form a prefix per wave (causal): kv0 <= rbase+15
      if (kv0 <= rbase + 15) {
        // S = Q K^T from current kb (registers, loaded last iter)
        f32x4 s[4];
        __builtin_amdgcn_s_setprio(1);
#pragma unroll
        for (int ni = 0; ni < 4; ni++) {
          f32x4 z = {};
          z = __builtin_amdgcn_mfma_f32_16x16x32_bf16(qf[0], kb[ni][0], z, 0, 0, 0);
          z = __builtin_amdgcn_mfma_f32_16x16x32_bf16(qf[1], kb[ni][1], z, 0, 0, 0);
          s[ni] = z;
        }
        __builtin_amdgcn_s_setprio(0);
        // prefetch next tile's K frags (same regs; MFMAs above already consumed them).
        // L2 latency hides under the exp chain + PV below. Wave-uniform guard, exact:
        // next-iter-active == (it+1 < n_it) && (kv0+64 <= rbase+15).
        if ((it + 1 < n_it) && (kv0 + 64 <= rbase + 15)) {
          const unsigned short* Kn = Kf + (size_t)(kv0 + 64) * HD;
#pragma unroll
          for (int ni = 0; ni < 4; ni++) {
            kb[ni][0] = *(const bf16x8*)(Kn + (size_t)(ni * 16) * HD);
            kb[ni][1] = *(const bf16x8*)(Kn + (size_t)(ni * 16) * HD + 32);
          }
        }
        // P = exp2(S); mask only when the diagonal touches this wave (wave-uniform branch)
        if (kv0 + 63 > rbase) {
#pragma unroll
          for (int ni = 0; ni < 4; ni++) {
            const int col_g = kv0 + ni * 16 + l15;
#pragma unroll
            for (int r = 0; r < 4; r++) {
              const int row_g = rbase + quad * 4 + r;
              const float sv = (col_g <= row_g) ? s[ni][r] : -1e30f;
              Ps[w][quad * 4 + r][ni * 16 + l15] = f2bf_rtz(exp2f(sv));
            }
          }
        } else {
#pragma unroll
          for (int ni = 0; ni < 4; ni++)
#pragma unroll
            for (int r = 0; r < 4; r++)
              Ps[w][quad * 4 + r][ni * 16 + l15] = f2bf_rtz(exp2f(s[ni][r]));
        }
        // per-wave LDS round-trip: C-layout -> A-layout (intra-wave, lgkmcnt-ordered)
        bf16x8 pa[2];
        pa[0] = *(const bf16x8*)&Ps[w][l15][quad * 8];
        pa[1] = *(const bf16x8*)&Ps[w][l15][32 + quad * 8];
        // V fragments from current buffer
        bf16x8 vb[4][2];
#pragma unroll
        for (int nd = 0; nd < 4; nd++) {
          vb[nd][0] = *(const bf16x8*)&Vs[cur][nd * 16 + l15][quad * 8];
          vb[nd][1] = *(const bf16x8*)&Vs[cur][nd * 16 + l15][32 + quad * 8];
        }
        // l += row-sum(P) via ones-B MFMA; O += P @ V
        __builtin_amdgcn_s_setprio(1);
        l_acc = __builtin_amdgcn_mfma_f32_16x16x32_bf16(pa[0], ones, l_acc, 0, 0, 0);
        l_acc = __builtin_amdgcn_mfma_f32_16x16x32_bf16(pa[1], ones, l_acc, 0, 0, 0);
#pragma unroll
        for (int nd = 0; nd < 4; nd++) {
          o[nd] = __builtin_amdgcn_mfma_f32_16x16x32_bf16(pa[0], vb[nd][0], o[nd], 0, 0, 0);
          o[nd] = __builtin_amdgcn_mfma_f32_16x16x32_bf16(pa[1], vb[nd][1], o[nd], 0, 0, 0);
        }
        __builtin_amdgcn_s_setprio(0);
      }
      __syncthreads();  // single barrier: ends this iter (reads of Vs[cur] done; commits visible)
    }
    // epilogue: normalize and write [B,T,H*D]
    {
      float rin[4];
#pragma unroll
      for (int r = 0; r < 4; r++) rin[r] = __builtin_amdgcn_rcpf(l_acc[r]);
#pragma unroll
      for (int nd = 0; nd < 4; nd++)
#pragma unroll
        for (int r = 0; r < 4; r++) {
          const int row_g = rbase + quad * 4 + r;
          const size_t mg = (size_t)b * TT + row_g;
          AO[mg * CE + h * 64 + nd * 16 + l15] = f2bf(o[nd][r] * rin[r]);
        }
    }
  }
}

extern "C" void kernel_launch(void* const* d_in, const int* in_sizes, int n_in,
                              void* d_out, int out_size, void* d_ws, size_t ws_size,
                              hipStream_t stream) {
  const float* x     = (const float*)d_in[0];  // [4,2048,1024] f32
  const float* w_qkv = (const float*)d_in[1];  // [1024,3072] f32
  const float* w_out = (const float*)d_in[2];  // [1024,1024] f32
  const float* b_out = (const float*)d_in[3];  // [1024] f32
  float* out = (float*)d_out;                  // [4,2048,1024] f32

  unsigned short* ws  = (unsigned short*)d_ws;
  unsigned short* Xb  = ws;                                  // x bf16 [8192][1024]
  unsigned short* Wt1 = Xb  + (size_t)MM * CE;               // w_qkv^T  [3072][1024]
  unsigned short* Wt2 = Wt1 + (size_t)3072 * 1024;           // w_out^T  [1024][1024]
  unsigned short* Qb  = Wt2 + (size_t)1024 * 1024;           // [BH][T][64]
  unsigned short* Kb  = Qb  + (size_t)8388608;               // [BH][T][64]
  unsigned short* Vb  = Kb  + (size_t)8388608;               // [BH][T][64]
  unsigned short* Vtb = Vb  + (size_t)8388608;               // [BH][64][T]
  unsigned short* AO  = Vtb + (size_t)8388608;               // [M][1024] bf16

  convert_x     <<<dim3(8192), 256, 0, stream>>>(x, Xb);
  transpose_conv<<<dim3(96, 32), 256, 0, stream>>>(w_qkv, Wt1, 1024, 3072);
  transpose_conv<<<dim3(32, 32), 256, 0, stream>>>(w_out, Wt2, 1024, 1024);
  gemm_qkv  <<<dim3(24, 64), 256, 0, stream>>>(Xb, Wt1, Qb, Kb, Vb);
  transpose_v<<<dim3(2, 64, 64), 256, 0, stream>>>(Vb, Vtb);
  flash_attn<<<dim3(8, 64), 512, 0, stream>>>(Qb, Kb, Vtb, AO);
  gemm_out  <<<dim3(8, 64), 256, 0, stream>>>(AO, Wt2, b_out, out);
}

// Round 7
// 301.394 us; speedup vs baseline: 1.3860x; 1.0995x over previous
//
#include <hip/hip_runtime.h>

// Problem constants
#define NH 16
#define HD 64
#define CE 1024
#define TT 2048
#define BB 4
#define MM 8192   // B*T

using bf16x8 = __attribute__((ext_vector_type(8))) __bf16;
using f32x4  = __attribute__((ext_vector_type(4))) float;

__device__ __forceinline__ unsigned short f2bf(float f) {
  unsigned int u = __float_as_uint(f);
  u += 0x7fffu + ((u >> 16) & 1u);   // RNE
  return (unsigned short)(u >> 16);
}
__device__ __forceinline__ unsigned short f2bf_rtz(float f) {
  return (unsigned short)(__float_as_uint(f) >> 16);  // truncate: 1-op, used for P only
}

// async global->LDS, 16B per lane; LDS dst must be wave-uniform (HW adds lane*16)
__device__ __forceinline__ void async_cp16(const unsigned short* g, unsigned short* l) {
  __builtin_amdgcn_global_load_lds(
      (const __attribute__((address_space(1))) unsigned int*)g,
      (__attribute__((address_space(3))) unsigned int*)l, 16, 0, 0);
}

// ---------------- fp32 -> bf16 convert (x) ----------------
__global__ __launch_bounds__(256) void convert_x(const float* __restrict__ in,
                                                 unsigned short* __restrict__ out) {
  const int i = (blockIdx.x * 256 + threadIdx.x) * 4;
  const float4 v = *(const float4*)(in + i);
  ushort4 o;
  o.x = f2bf(v.x); o.y = f2bf(v.y); o.z = f2bf(v.z); o.w = f2bf(v.w);
  *(ushort4*)(out + i) = o;
}

// ------------- transpose + fp32->bf16: in[rows][cols] f32 -> out[cols][rows] bf16 -------------
__global__ __launch_bounds__(256) void transpose_conv(const float* __restrict__ in,
                                                      unsigned short* __restrict__ out,
                                                      int rows, int cols) {
  __shared__ unsigned short tile[32][33];
  int c0 = blockIdx.x * 32, r0 = blockIdx.y * 32;
  int tx = threadIdx.x & 31, ty = threadIdx.x >> 5;  // ty 0..7
#pragma unroll
  for (int i = ty; i < 32; i += 8)
    tile[i][tx] = f2bf(in[(size_t)(r0 + i) * cols + c0 + tx]);
  __syncthreads();
#pragma unroll
  for (int i = ty; i < 32; i += 8)
    out[(size_t)(c0 + i) * rows + r0 + tx] = tile[tx][i];
}

// ------------- per-head V transpose (bf16): in[bh][2048][64] -> out[bh][64][2048] -------------
__global__ __launch_bounds__(256) void transpose_v(const unsigned short* __restrict__ in,
                                                   unsigned short* __restrict__ out) {
  __shared__ unsigned short tile[32][33];
  const int bh = blockIdx.z;
  const int t0 = blockIdx.y * 32, d0 = blockIdx.x * 32;
  const int tx = threadIdx.x & 31, ty = threadIdx.x >> 5;
  const size_t base = (size_t)bh * TT * HD;
#pragma unroll
  for (int i = ty; i < 32; i += 8)
    tile[i][tx] = in[base + (size_t)(t0 + i) * HD + d0 + tx];
  __syncthreads();
#pragma unroll
  for (int i = ty; i < 32; i += 8)
    out[base + (size_t)(d0 + i) * TT + t0 + tx] = tile[tx][i];
}

// ---------------- GEMM core (m97 structure): C[128x128] tile of A[M,1024] @ BT[N,1024]^T --------
__device__ __forceinline__ void gemm_core(const unsigned short* __restrict__ A,
                                          const unsigned short* __restrict__ BT,
                                          int m0, int n0, f32x4 (&acc)[4][4]) {
  __shared__ unsigned short As[128 * 32];
  __shared__ unsigned short Bs[128 * 32];
  const int tid  = threadIdx.x;
  const int lane = tid & 63;
  const int wave = tid >> 6;
  const int quad = lane >> 4;
  const int l15  = lane & 15;
  const int wm = (wave & 1) * 64;
  const int wn = (wave >> 1) * 64;
  const int ldr = tid >> 2;         // 0..63
  const int ldc = (tid & 3) * 8;    // 0,8,16,24
  const unsigned short* Ap = A + (size_t)(m0 + ldr) * CE + ldc;
  const unsigned short* Bp = BT + (size_t)(n0 + ldr) * CE + ldc;
  unsigned short* AsW0 = As + wave * 512;          // wave-uniform LDS dst, rows 0..63
  unsigned short* AsW1 = As + 2048 + wave * 512;   // rows 64..127
  unsigned short* BsW0 = Bs + wave * 512;
  unsigned short* BsW1 = Bs + 2048 + wave * 512;
  for (int k0 = 0; k0 < CE; k0 += 32) {
    async_cp16(Ap + k0, AsW0);
    async_cp16(Ap + (size_t)64 * CE + k0, AsW1);
    async_cp16(Bp + k0, BsW0);
    async_cp16(Bp + (size_t)64 * CE + k0, BsW1);
    __syncthreads();   // compiler emits vmcnt(0) drain before barrier
    bf16x8 af[4], bfr[4];
#pragma unroll
    for (int i = 0; i < 4; i++) {
      af[i]  = *(const bf16x8*)&As[(wm + i * 16 + l15) * 32 + quad * 8];
      bfr[i] = *(const bf16x8*)&Bs[(wn + i * 16 + l15) * 32 + quad * 8];
    }
#pragma unroll
    for (int mi = 0; mi < 4; mi++)
#pragma unroll
      for (int ni = 0; ni < 4; ni++)
        acc[mi][ni] = __builtin_amdgcn_mfma_f32_16x16x32_bf16(af[mi], bfr[ni], acc[mi][ni], 0, 0, 0);
    __syncthreads();
  }
}

// ---------------- GEMM 1: qkv = x @ w_qkv, scattered into Q (scaled), K, V (coalesced) ---------
// Q pre-scaled by HD^-0.5 * log2(e): flash computes exp2(s) == exp(s / log2e) exactly.
__global__ __launch_bounds__(256) void gemm_qkv(const unsigned short* __restrict__ A,
                                                const unsigned short* __restrict__ BT,
                                                unsigned short* __restrict__ Qb,
                                                unsigned short* __restrict__ Kb,
                                                unsigned short* __restrict__ Vb) {
  f32x4 acc[4][4] = {};
  const int m0 = blockIdx.y * 128, n0 = blockIdx.x * 128;
  gemm_core(A, BT, m0, n0, acc);
  const int tid = threadIdx.x, lane = tid & 63, wave = tid >> 6;
  const int quad = lane >> 4, l15 = lane & 15;
  const int wm = (wave & 1) * 64, wn = (wave >> 1) * 64;
  const float QSCALE = 0.125f * 1.44269504088896340736f;
#pragma unroll
  for (int mi = 0; mi < 4; mi++) {
#pragma unroll
    for (int ni = 0; ni < 4; ni++) {
      const int n = n0 + wn + ni * 16 + l15;
      const int s = n >> 10;           // 0=q 1=k 2=v
      const int h = (n >> 6) & 15;
      const int d = n & 63;
#pragma unroll
      for (int r = 0; r < 4; r++) {
        const int m = m0 + wm + mi * 16 + quad * 4 + r;
        const int b = m >> 11;         // /2048
        const int t = m & 2047;
        const int bh = (b << 4) + h;
        const float v = acc[mi][ni][r];
        if (s == 0)      Qb[((size_t)bh * TT + t) * HD + d] = f2bf(v * QSCALE);
        else if (s == 1) Kb[((size_t)bh * TT + t) * HD + d] = f2bf(v);
        else             Vb[((size_t)bh * TT + t) * HD + d] = f2bf(v);
      }
    }
  }
}

// ---------------- GEMM 2: out = AO @ w_out + b_out (fp32 out) ----------------
__global__ __launch_bounds__(256) void gemm_out(const unsigned short* __restrict__ A,
                                                const unsigned short* __restrict__ BT,
                                                const float* __restrict__ bias,
                                                float* __restrict__ out) {
  f32x4 acc[4][4] = {};
  const int m0 = blockIdx.y * 128, n0 = blockIdx.x * 128;
  gemm_core(A, BT, m0, n0, acc);
  const int tid = threadIdx.x, lane = tid & 63, wave = tid >> 6;
  const int quad = lane >> 4, l15 = lane & 15;
  const int wm = (wave & 1) * 64, wn = (wave >> 1) * 64;
#pragma unroll
  for (int mi = 0; mi < 4; mi++) {
#pragma unroll
    for (int ni = 0; ni < 4; ni++) {
      const int n = n0 + wn + ni * 16 + l15;
      const float bv = bias[n];
#pragma unroll
      for (int r = 0; r < 4; r++) {
        const int m = m0 + wm + mi * 16 + quad * 4 + r;
        out[(size_t)m * CE + n] = acc[mi][ni][r] + bv;
      }
    }
  }
}

// ---------------- causal flash attention: 8 waves, TWO concurrent 128-row Q tiles --------------
// Recombination of the two verified parents:
//   R4 (77.5us): 512 thr / 8 waves sharing each staged KV tile -> 16 waves/CU.
//   R0 (127us): 2 m-frags (32 Q rows) per wave -> K/V LDS reads amortized over 2x rows.
// Waves 0-3 own q-tile qx, waves 4-7 own q-tile 15-qx, processed CONCURRENTLY over a single
// block-uniform KV sweep (n_it = 32-2*qx = the larger tile's need). Benefits vs R4:
// block-iters 17408 -> 12800 (-26%), K/V LDS re-reads per unit work halved, barriers -26%,
// same occupancy (2 blocks x 8 waves /CU), VGPR ~= R0's 96. Staging pattern, T1 XCD swizzle
// (verified: FETCH 152->24.6MB), T5 setprio, pad-72 all byte-identical to R4.
__global__ __launch_bounds__(512) void flash_attn(const unsigned short* __restrict__ Q,
                                                  const unsigned short* __restrict__ Kg,
                                                  const unsigned short* __restrict__ Vt,
                                                  unsigned short* __restrict__ AO) {
  __shared__ unsigned short Ks[64][72];     // [kv][d]
  __shared__ unsigned short Vs[64][72];     // [d][kv]
  __shared__ unsigned short Ps[8][32][72];  // per-wave P, [qrow 0..31][kv]
  // T1 chunked swizzle: hw assigns flat%8 -> XCD; XCD c gets wu in [64c,64c+64)
  const int flat = blockIdx.x + 8 * blockIdx.y;        // 0..511, hw dispatch order
  const int wu   = (flat & 7) * 64 + (flat >> 3);      // bijective remap
  const int qx   = wu & 7;                             // q-tile index 0..7
  const int bh   = wu >> 3;                            // head 0..63 (8 consecutive heads/XCD)
  const int tid = threadIdx.x, w = tid >> 6, lane = tid & 63;
  const int quad = lane >> 4, l15 = lane & 15;
  const int w2 = w & 3;                                // wave within its tile group
  const int tq = (w >> 2) ? (15 - qx) : qx;            // this wave's q-tile
  const int b = bh >> 4, h = bh & 15;
  const unsigned short* Kbase = Kg + (size_t)bh * TT * HD;
  const unsigned short* Vbase = Vt + (size_t)bh * HD * TT;
  const int srow = tid >> 3;        // 0..63
  const int scol = (tid & 7) * 8;   // 0..56 ushorts (16B chunks)
  const bf16x8 ones = {1, 1, 1, 1, 1, 1, 1, 1};

  const int q0 = tq * 128;
  const int wr = q0 + w2 * 32;            // this wave's first Q row (32 rows)
  const int n_it = 32 - 2 * qx;           // block-uniform: covers the larger tile (15-qx)

  // Q fragments: 2 m-frags per wave; A[m=l15][k=quad*8+j (+32)]
  bf16x8 qf[2][2];
#pragma unroll
  for (int mi = 0; mi < 2; mi++) {
    const unsigned short* Qp =
        Q + ((size_t)bh * TT + wr + mi * 16 + l15) * HD + quad * 8;
    qf[mi][0] = *(const bf16x8*)Qp;
    qf[mi][1] = *(const bf16x8*)(Qp + 32);
  }
  f32x4 o[2][4] = {};
  f32x4 l_acc[2] = {};
  // initial prefetch (tile 0)
  uint4 kreg, vreg;
  {
    kreg = *(const uint4*)(Kbase + (size_t)srow * HD + scol);
    vreg = *(const uint4*)(Vbase + (size_t)srow * TT + scol);
  }
  for (int it = 0; it < n_it; it++) {
    const int kv0 = it * 64;
    // commit prefetched tile to LDS
    *(uint4*)&Ks[srow][scol] = kreg;
    *(uint4*)&Vs[srow][scol] = vreg;
    // issue next tile's loads BEFORE the barrier; they fly across it and during compute
    {
      const int itn = (it + 1 < n_it) ? it + 1 : it;
      const int kvn = itn * 64;
      kreg = *(const uint4*)(Kbase + (size_t)(kvn + srow) * HD + scol);
      vreg = *(const uint4*)(Vbase + (size_t)srow * TT + kvn + scol);
    }
    __syncthreads();
    // waves fully above this KV tile produce all-zero P: skip (wave-uniform)
    if (kv0 <= wr + 31) {
      // K fragments (shared across both m-frags)
      bf16x8 kb[4][2];
#pragma unroll
      for (int ni = 0; ni < 4; ni++) {
        kb[ni][0] = *(const bf16x8*)&Ks[ni * 16 + l15][quad * 8];
        kb[ni][1] = *(const bf16x8*)&Ks[ni * 16 + l15][32 + quad * 8];
      }
      // S = Q K^T
      f32x4 s[2][4];
      __builtin_amdgcn_s_setprio(1);
#pragma unroll
      for (int mi = 0; mi < 2; mi++)
#pragma unroll
        for (int ni = 0; ni < 4; ni++) {
          f32x4 z = {};
          z = __builtin_amdgcn_mfma_f32_16x16x32_bf16(qf[mi][0], kb[ni][0], z, 0, 0, 0);
          z = __builtin_amdgcn_mfma_f32_16x16x32_bf16(qf[mi][1], kb[ni][1], z, 0, 0, 0);
          s[mi][ni] = z;
        }
      __builtin_amdgcn_s_setprio(0);
      // V fragments (independent of P: their lgkm waits overlap the exp chain below)
      bf16x8 vb[4][2];
#pragma unroll
      for (int nd = 0; nd < 4; nd++) {
        vb[nd][0] = *(const bf16x8*)&Vs[nd * 16 + l15][quad * 8];
        vb[nd][1] = *(const bf16x8*)&Vs[nd * 16 + l15][32 + quad * 8];
      }
      // P = exp2(S); mask only frags the diagonal touches (wave-uniform branch per m-frag)
#pragma unroll
      for (int mi = 0; mi < 2; mi++) {
        const int rb = wr + mi * 16;
        if (kv0 + 63 > rb) {
#pragma unroll
          for (int ni = 0; ni < 4; ni++) {
            const int col_g = kv0 + ni * 16 + l15;
#pragma unroll
            for (int r = 0; r < 4; r++) {
              const int row_g = rb + quad * 4 + r;
              const float sv = (col_g <= row_g) ? s[mi][ni][r] : -1e30f;
              Ps[w][mi * 16 + quad * 4 + r][ni * 16 + l15] = f2bf_rtz(exp2f(sv));
            }
          }
        } else {
#pragma unroll
          for (int ni = 0; ni < 4; ni++)
#pragma unroll
            for (int r = 0; r < 4; r++)
              Ps[w][mi * 16 + quad * 4 + r][ni * 16 + l15] = f2bf_rtz(exp2f(s[mi][ni][r]));
        }
      }
      // per-wave LDS round-trip: C-layout -> A-layout (intra-wave, lgkmcnt-ordered)
      bf16x8 pa[2][2];
#pragma unroll
      for (int mi = 0; mi < 2; mi++) {
        pa[mi][0] = *(const bf16x8*)&Ps[w][mi * 16 + l15][quad * 8];
        pa[mi][1] = *(const bf16x8*)&Ps[w][mi * 16 + l15][32 + quad * 8];
      }
      // l += row-sum(P) via ones-B MFMA; O += P @ V
      __builtin_amdgcn_s_setprio(1);
#pragma unroll
      for (int mi = 0; mi < 2; mi++) {
        l_acc[mi] = __builtin_amdgcn_mfma_f32_16x16x32_bf16(pa[mi][0], ones, l_acc[mi], 0, 0, 0);
        l_acc[mi] = __builtin_amdgcn_mfma_f32_16x16x32_bf16(pa[mi][1], ones, l_acc[mi], 0, 0, 0);
      }
#pragma unroll
      for (int mi = 0; mi < 2; mi++)
#pragma unroll
        for (int nd = 0; nd < 4; nd++) {
          o[mi][nd] = __builtin_amdgcn_mfma_f32_16x16x32_bf16(pa[mi][0], vb[nd][0], o[mi][nd], 0, 0, 0);
          o[mi][nd] = __builtin_amdgcn_mfma_f32_16x16x32_bf16(pa[mi][1], vb[nd][1], o[mi][nd], 0, 0, 0);
        }
      __builtin_amdgcn_s_setprio(0);
    }
    __syncthreads();  // LDS reads done before next iteration's commit
  }
  // epilogue: normalize and write [B,T,H*D]
#pragma unroll
  for (int mi = 0; mi < 2; mi++) {
    float rin[4];
#pragma unroll
    for (int r = 0; r < 4; r++) rin[r] = __builtin_amdgcn_rcpf(l_acc[mi][r]);
#pragma unroll
    for (int nd = 0; nd < 4; nd++)
#pragma unroll
      for (int r = 0; r < 4; r++) {
        const int row_g = wr + mi * 16 + quad * 4 + r;
        const size_t mg = (size_t)b * TT + row_g;
        AO[mg * CE + h * 64 + nd * 16 + l15] = f2bf(o[mi][nd][r] * rin[r]);
      }
  }
}

extern "C" void kernel_launch(void* const* d_in, const int* in_sizes, int n_in,
                              void* d_out, int out_size, void* d_ws, size_t ws_size,
                              hipStream_t stream) {
  const float* x     = (const float*)d_in[0];  // [4,2048,1024] f32
  const float* w_qkv = (const float*)d_in[1];  // [1024,3072] f32
  const float* w_out = (const float*)d_in[2];  // [1024,1024] f32
  const float* b_out = (const float*)d_in[3];  // [1024] f32
  float* out = (float*)d_out;                  // [4,2048,1024] f32

  unsigned short* ws  = (unsigned short*)d_ws;
  unsigned short* Xb  = ws;                                  // x bf16 [8192][1024]
  unsigned short* Wt1 = Xb  + (size_t)MM * CE;               // w_qkv^T  [3072][1024]
  unsigned short* Wt2 = Wt1 + (size_t)3072 * 1024;           // w_out^T  [1024][1024]
  unsigned short* Qb  = Wt2 + (size_t)1024 * 1024;           // [BH][T][64]
  unsigned short* Kb  = Qb  + (size_t)8388608;               // [BH][T][64]
  unsigned short* Vb  = Kb  + (size_t)8388608;               // [BH][T][64]
  unsigned short* Vtb = Vb  + (size_t)8388608;               // [BH][64][T]
  unsigned short* AO  = Vtb + (size_t)8388608;               // [M][1024] bf16

  convert_x     <<<dim3(8192), 256, 0, stream>>>(x, Xb);
  transpose_conv<<<dim3(96, 32), 256, 0, stream>>>(w_qkv, Wt1, 1024, 3072);
  transpose_conv<<<dim3(32, 32), 256, 0, stream>>>(w_out, Wt2, 1024, 1024);
  gemm_qkv  <<<dim3(24, 64), 256, 0, stream>>>(Xb, Wt1, Qb, Kb, Vb);
  transpose_v<<<dim3(2, 64, 64), 256, 0, stream>>>(Vb, Vtb);
  flash_attn<<<dim3(8, 64), 512, 0, stream>>>(Qb, Kb, Vtb, AO);
  gemm_out  <<<dim3(8, 64), 256, 0, stream>>>(AO, Wt2, b_out, out);
}

// Round 8
// 263.583 us; speedup vs baseline: 1.5849x; 1.1435x over previous
//
#include <hip/hip_runtime.h>

// Problem constants
#define NH 16
#define HD 64
#define CE 1024
#define TT 2048
#define BB 4
#define MM 8192   // B*T

using bf16x8 = __attribute__((ext_vector_type(8))) __bf16;
using f32x4  = __attribute__((ext_vector_type(4))) float;

__device__ __forceinline__ unsigned short f2bf(float f) {
  unsigned int u = __float_as_uint(f);
  u += 0x7fffu + ((u >> 16) & 1u);   // RNE
  return (unsigned short)(u >> 16);
}
__device__ __forceinline__ unsigned short f2bf_rtz(float f) {
  return (unsigned short)(__float_as_uint(f) >> 16);  // truncate: 1-op, used for P only
}

// async global->LDS, 16B per lane; LDS dst must be wave-uniform (HW adds lane*16)
__device__ __forceinline__ void async_cp16(const unsigned short* g, unsigned short* l) {
  __builtin_amdgcn_global_load_lds(
      (const __attribute__((address_space(1))) unsigned int*)g,
      (__attribute__((address_space(3))) unsigned int*)l, 16, 0, 0);
}

// ---------------- fused prep: convert_x + transpose(w_qkv) + transpose(w_out) ------------------
// Grid partition (one launch instead of three):
//   [0, 8192):        x f32 -> bf16 copy
//   [8192, 11264):    w_qkv [1024][3072] f32 -> [3072][1024] bf16 (tc: bx=tc%96, by=tc/96)
//   [11264, 12288):   w_out [1024][1024] f32 -> [1024][1024]^T bf16 (tc: bx=tc%32, by=tc/32)
__global__ __launch_bounds__(256) void prep(const float* __restrict__ x,
                                            const float* __restrict__ w_qkv,
                                            const float* __restrict__ w_out,
                                            unsigned short* __restrict__ Xb,
                                            unsigned short* __restrict__ Wt1,
                                            unsigned short* __restrict__ Wt2) {
  __shared__ unsigned short tile[32][33];
  const int idx = blockIdx.x;
  if (idx < 8192) {
    const int i = (idx * 256 + threadIdx.x) * 4;
    const float4 v = *(const float4*)(x + i);
    ushort4 o;
    o.x = f2bf(v.x); o.y = f2bf(v.y); o.z = f2bf(v.z); o.w = f2bf(v.w);
    *(ushort4*)(Xb + i) = o;
    return;
  }
  const float* in;
  unsigned short* out;
  int rows, cols, bx, by;
  if (idx < 11264) {
    const int tc = idx - 8192;
    in = w_qkv; out = Wt1; rows = 1024; cols = 3072;
    bx = tc % 96; by = tc / 96;
  } else {
    const int tc = idx - 11264;
    in = w_out; out = Wt2; rows = 1024; cols = 1024;
    bx = tc & 31; by = tc >> 5;
  }
  const int c0 = bx * 32, r0 = by * 32;
  const int tx = threadIdx.x & 31, ty = threadIdx.x >> 5;  // ty 0..7
#pragma unroll
  for (int i = ty; i < 32; i += 8)
    tile[i][tx] = f2bf(in[(size_t)(r0 + i) * cols + c0 + tx]);
  __syncthreads();
#pragma unroll
  for (int i = ty; i < 32; i += 8)
    out[(size_t)(c0 + i) * rows + r0 + tx] = tile[tx][i];
}

// ---------------- GEMM core (m97 structure): C[128x128] tile of A[M,1024] @ BT[N,1024]^T --------
// As/Bs passed in so callers can alias the LDS pool for epilogue reuse.
__device__ __forceinline__ void gemm_core(const unsigned short* __restrict__ A,
                                          const unsigned short* __restrict__ BT,
                                          int m0, int n0, f32x4 (&acc)[4][4],
                                          unsigned short* As, unsigned short* Bs) {
  const int tid  = threadIdx.x;
  const int lane = tid & 63;
  const int wave = tid >> 6;
  const int quad = lane >> 4;
  const int l15  = lane & 15;
  const int wm = (wave & 1) * 64;
  const int wn = (wave >> 1) * 64;
  const int ldr = tid >> 2;         // 0..63
  const int ldc = (tid & 3) * 8;    // 0,8,16,24
  const unsigned short* Ap = A + (size_t)(m0 + ldr) * CE + ldc;
  const unsigned short* Bp = BT + (size_t)(n0 + ldr) * CE + ldc;
  unsigned short* AsW0 = As + wave * 512;          // wave-uniform LDS dst, rows 0..63
  unsigned short* AsW1 = As + 2048 + wave * 512;   // rows 64..127
  unsigned short* BsW0 = Bs + wave * 512;
  unsigned short* BsW1 = Bs + 2048 + wave * 512;
  for (int k0 = 0; k0 < CE; k0 += 32) {
    async_cp16(Ap + k0, AsW0);
    async_cp16(Ap + (size_t)64 * CE + k0, AsW1);
    async_cp16(Bp + k0, BsW0);
    async_cp16(Bp + (size_t)64 * CE + k0, BsW1);
    __syncthreads();   // compiler emits vmcnt(0) drain before barrier
    bf16x8 af[4], bfr[4];
#pragma unroll
    for (int i = 0; i < 4; i++) {
      af[i]  = *(const bf16x8*)&As[(wm + i * 16 + l15) * 32 + quad * 8];
      bfr[i] = *(const bf16x8*)&Bs[(wn + i * 16 + l15) * 32 + quad * 8];
    }
#pragma unroll
    for (int mi = 0; mi < 4; mi++)
#pragma unroll
      for (int ni = 0; ni < 4; ni++)
        acc[mi][ni] = __builtin_amdgcn_mfma_f32_16x16x32_bf16(af[mi], bfr[ni], acc[mi][ni], 0, 0, 0);
    __syncthreads();
  }
}

// ---------------- GEMM 1: qkv = x @ w_qkv -> Q (scaled), K, and V written TRANSPOSED -----------
// Q pre-scaled by HD^-0.5 * log2(e): flash computes exp2(s) == exp(s / log2e) exactly.
// Blocks bx<8: Q, bx 8..15: K (direct [bh][t][d] writes). Blocks bx>=16: V — the 128x128 tile
// is bounced through LDS in [d][t] layout (2 passes of 64 t, pad 66: store banks = 33*row+col/2,
// read banks = 33*d+lane, both conflict-free) and written to Vtb[bh][d][t] with coalesced u32
// stores. This replaces the separate transpose_v kernel (saves its dispatch + 33MB traffic).
__global__ __launch_bounds__(256) void gemm_qkv(const unsigned short* __restrict__ A,
                                                const unsigned short* __restrict__ BT,
                                                unsigned short* __restrict__ Qb,
                                                unsigned short* __restrict__ Kb,
                                                unsigned short* __restrict__ Vtb) {
  __shared__ unsigned short pool[8448];   // As[4096] | Bs[4096]; V-epilogue aliases as [128][66]
  f32x4 acc[4][4] = {};
  const int m0 = blockIdx.y * 128, n0 = blockIdx.x * 128;
  gemm_core(A, BT, m0, n0, acc, pool, pool + 4096);
  const int tid = threadIdx.x, lane = tid & 63, wave = tid >> 6;
  const int quad = lane >> 4, l15 = lane & 15;
  const int wm = (wave & 1) * 64, wn = (wave >> 1) * 64;
  if (blockIdx.x >= 16) {
    // ---- V: transpose tile through LDS, write Vtb[bh][d][t] coalesced ----
    unsigned short* Vt = pool;                 // [128 d][66], aliases As/Bs (safe after last sync)
    const int h0 = 2 * (blockIdx.x - 16);      // first head of this 128-col tile
    const int bb = m0 >> 11;                   // batch (tile never crosses: 2048%128==0)
    const int t0g = m0 & 2047;
    const int l31 = tid & 31;
    const int rw  = tid >> 5;                  // 0..7
    unsigned int* __restrict__ VtU = (unsigned int*)Vtb;
#pragma unroll
    for (int hp = 0; hp < 2; hp++) {           // two passes of 64 t-rows
      __syncthreads();                         // prior pass reads (or gemm reads) done
      if ((wave & 1) == hp) {                  // waves whose wm == 64*hp own these t rows
#pragma unroll
        for (int mi = 0; mi < 4; mi++)
#pragma unroll
          for (int ni = 0; ni < 4; ni++) {
            const int row = wn + ni * 16 + l15;      // d-local 0..127
            const int col = mi * 16 + quad * 4;      // t-local 0..63 (+r)
#pragma unroll
            for (int r = 0; r < 4; r++)
              Vt[row * 66 + col + r] = f2bf(acc[mi][ni][r]);
          }
      }
      __syncthreads();
      // write out: 128 d-rows x 32 u32 (64 t), 8 rows in parallel
#pragma unroll
      for (int k = 0; k < 16; k++) {
        const int d = rw + 8 * k;              // 0..127
        const unsigned int v = *(const unsigned int*)&Vt[d * 66 + 2 * l31];
        const int hh = h0 + (d >> 6);
        VtU[((((size_t)(bb * 16 + hh) * 64 + (d & 63)) * TT + t0g + 64 * hp) >> 1) + l31] = v;
      }
    }
    return;
  }
  // ---- Q / K: direct scatter (coalesced over l15 -> d) ----
  const float QSCALE = 0.125f * 1.44269504088896340736f;
#pragma unroll
  for (int mi = 0; mi < 4; mi++) {
#pragma unroll
    for (int ni = 0; ni < 4; ni++) {
      const int n = n0 + wn + ni * 16 + l15;
      const int s = n >> 10;           // 0=q 1=k
      const int h = (n >> 6) & 15;
      const int d = n & 63;
#pragma unroll
      for (int r = 0; r < 4; r++) {
        const int m = m0 + wm + mi * 16 + quad * 4 + r;
        const int b = m >> 11;         // /2048
        const int t = m & 2047;
        const int bh = (b << 4) + h;
        const float v = acc[mi][ni][r];
        if (s == 0) Qb[((size_t)bh * TT + t) * HD + d] = f2bf(v * QSCALE);
        else        Kb[((size_t)bh * TT + t) * HD + d] = f2bf(v);
      }
    }
  }
}

// ---------------- GEMM 2: out = AO @ w_out + b_out (fp32 out) ----------------
__global__ __launch_bounds__(256) void gemm_out(const unsigned short* __restrict__ A,
                                                const unsigned short* __restrict__ BT,
                                                const float* __restrict__ bias,
                                                float* __restrict__ out) {
  __shared__ unsigned short pool[8192];
  f32x4 acc[4][4] = {};
  const int m0 = blockIdx.y * 128, n0 = blockIdx.x * 128;
  gemm_core(A, BT, m0, n0, acc, pool, pool + 4096);
  const int tid = threadIdx.x, lane = tid & 63, wave = tid >> 6;
  const int quad = lane >> 4, l15 = lane & 15;
  const int wm = (wave & 1) * 64, wn = (wave >> 1) * 64;
#pragma unroll
  for (int mi = 0; mi < 4; mi++) {
#pragma unroll
    for (int ni = 0; ni < 4; ni++) {
      const int n = n0 + wn + ni * 16 + l15;
      const float bv = bias[n];
#pragma unroll
      for (int r = 0; r < 4; r++) {
        const int m = m0 + wm + mi * 16 + quad * 4 + r;
        out[(size_t)m * CE + n] = acc[mi][ni][r] + bv;
      }
    }
  }
}

// ---------------- causal flash attention: round-4 verified kernel, VERBATIM --------------------
// 512 thr / 8 waves; wave owns 16 Q rows. KV tile 64 staged once per block, shared by 8 waves.
// One-iteration-ahead register prefetch issued BEFORE the barrier. T1 XCD-chunked swizzle
// (verified: FETCH 152 -> 24.6 MB). T5 setprio. Block pairs q-tiles qx and 15-qx: 34 iters
// every block (perfect balance — R7 showed breaking this costs more than any LDS saving).
__global__ __launch_bounds__(512) void flash_attn(const unsigned short* __restrict__ Q,
                                                  const unsigned short* __restrict__ Kg,
                                                  const unsigned short* __restrict__ Vt,
                                                  unsigned short* __restrict__ AO) {
  __shared__ unsigned short Ks[64][72];     // [kv][d]
  __shared__ unsigned short Vs[64][72];     // [d][kv]
  __shared__ unsigned short Ps[8][16][72];  // per-wave P, [qrow 0..15][kv]
  const int flat = blockIdx.x + 8 * blockIdx.y;        // 0..511, hw dispatch order
  const int wu   = (flat & 7) * 64 + (flat >> 3);      // bijective remap
  const int qx   = wu & 7;                             // q-tile index 0..7
  const int bh   = wu >> 3;                            // head 0..63 (8 consecutive heads/XCD)
  const int tid = threadIdx.x, w = tid >> 6, lane = tid & 63;
  const int quad = lane >> 4, l15 = lane & 15;
  const int b = bh >> 4, h = bh & 15;
  const unsigned short* Kbase = Kg + (size_t)bh * TT * HD;
  const unsigned short* Vbase = Vt + (size_t)bh * HD * TT;
  const int srow = tid >> 3;        // 0..63
  const int scol = (tid & 7) * 8;   // 0..56 (x2B = 16B chunks)
  const bf16x8 ones = {1, 1, 1, 1, 1, 1, 1, 1};

  for (int ph = 0; ph < 2; ph++) {
    const int pt = ph ? (15 - qx) : qx;
    const int q0 = pt * 128;
    const int n_it = 2 * pt + 2;
    const int rbase = q0 + w * 16;    // this wave's first Q row
    bf16x8 qf[2];
    {
      const unsigned short* Qp =
          Q + ((size_t)bh * TT + rbase + l15) * HD + quad * 8;
      qf[0] = *(const bf16x8*)Qp;
      qf[1] = *(const bf16x8*)(Qp + 32);
    }
    f32x4 o[4] = {};
    f32x4 l_acc = {};
    uint4 kreg, vreg;
    {
      kreg = *(const uint4*)(Kbase + (size_t)srow * HD + scol);
      vreg = *(const uint4*)(Vbase + (size_t)srow * TT + scol);
    }
    for (int it = 0; it < n_it; it++) {
      const int kv0 = it * 64;
      *(uint4*)&Ks[srow][scol] = kreg;
      *(uint4*)&Vs[srow][scol] = vreg;
      {
        const int itn = (it + 1 < n_it) ? it + 1 : it;
        const int kvn = itn * 64;
        kreg = *(const uint4*)(Kbase + (size_t)(kvn + srow) * HD + scol);
        vreg = *(const uint4*)(Vbase + (size_t)srow * TT + kvn + scol);
      }
      __syncthreads();
      if (kv0 <= rbase + 15) {
        bf16x8 kb[4][2];
#pragma unroll
        for (int ni = 0; ni < 4; ni++) {
          kb[ni][0] = *(const bf16x8*)&Ks[ni * 16 + l15][quad * 8];
          kb[ni][1] = *(const bf16x8*)&Ks[ni * 16 + l15][32 + quad * 8];
        }
        f32x4 s[4];
        __builtin_amdgcn_s_setprio(1);
#pragma unroll
        for (int ni = 0; ni < 4; ni++) {
          f32x4 z = {};
          z = __builtin_amdgcn_mfma_f32_16x16x32_bf16(qf[0], kb[ni][0], z, 0, 0, 0);
          z = __builtin_amdgcn_mfma_f32_16x16x32_bf16(qf[1], kb[ni][1], z, 0, 0, 0);
          s[ni] = z;
        }
        __builtin_amdgcn_s_setprio(0);
        if (kv0 + 63 > rbase) {
#pragma unroll
          for (int ni = 0; ni < 4; ni++) {
            const int col_g = kv0 + ni * 16 + l15;
#pragma unroll
            for (int r = 0; r < 4; r++) {
              const int row_g = rbase + quad * 4 + r;
              const float sv = (col_g <= row_g) ? s[ni][r] : -1e30f;
              Ps[w][quad * 4 + r][ni * 16 + l15] = f2bf_rtz(exp2f(sv));
            }
          }
        } else {
#pragma unroll
          for (int ni = 0; ni < 4; ni++)
#pragma unroll
            for (int r = 0; r < 4; r++)
              Ps[w][quad * 4 + r][ni * 16 + l15] = f2bf_rtz(exp2f(s[ni][r]));
        }
        bf16x8 pa[2];
        pa[0] = *(const bf16x8*)&Ps[w][l15][quad * 8];
        pa[1] = *(const bf16x8*)&Ps[w][l15][32 + quad * 8];
        bf16x8 vb[4][2];
#pragma unroll
        for (int nd = 0; nd < 4; nd++) {
          vb[nd][0] = *(const bf16x8*)&Vs[nd * 16 + l15][quad * 8];
          vb[nd][1] = *(const bf16x8*)&Vs[nd * 16 + l15][32 + quad * 8];
        }
        __builtin_amdgcn_s_setprio(1);
        l_acc = __builtin_amdgcn_mfma_f32_16x16x32_bf16(pa[0], ones, l_acc, 0, 0, 0);
        l_acc = __builtin_amdgcn_mfma_f32_16x16x32_bf16(pa[1], ones, l_acc, 0, 0, 0);
#pragma unroll
        for (int nd = 0; nd < 4; nd++) {
          o[nd] = __builtin_amdgcn_mfma_f32_16x16x32_bf16(pa[0], vb[nd][0], o[nd], 0, 0, 0);
          o[nd] = __builtin_amdgcn_mfma_f32_16x16x32_bf16(pa[1], vb[nd][1], o[nd], 0, 0, 0);
        }
        __builtin_amdgcn_s_setprio(0);
      }
      __syncthreads();
    }
    {
      float rin[4];
#pragma unroll
      for (int r = 0; r < 4; r++) rin[r] = __builtin_amdgcn_rcpf(l_acc[r]);
#pragma unroll
      for (int nd = 0; nd < 4; nd++)
#pragma unroll
        for (int r = 0; r < 4; r++) {
          const int row_g = rbase + quad * 4 + r;
          const size_t mg = (size_t)b * TT + row_g;
          AO[mg * CE + h * 64 + nd * 16 + l15] = f2bf(o[nd][r] * rin[r]);
        }
    }
  }
}

extern "C" void kernel_launch(void* const* d_in, const int* in_sizes, int n_in,
                              void* d_out, int out_size, void* d_ws, size_t ws_size,
                              hipStream_t stream) {
  const float* x     = (const float*)d_in[0];  // [4,2048,1024] f32
  const float* w_qkv = (const float*)d_in[1];  // [1024,3072] f32
  const float* w_out = (const float*)d_in[2];  // [1024,1024] f32
  const float* b_out = (const float*)d_in[3];  // [1024] f32
  float* out = (float*)d_out;                  // [4,2048,1024] f32

  unsigned short* ws  = (unsigned short*)d_ws;
  unsigned short* Xb  = ws;                                  // x bf16 [8192][1024]
  unsigned short* Wt1 = Xb  + (size_t)MM * CE;               // w_qkv^T  [3072][1024]
  unsigned short* Wt2 = Wt1 + (size_t)3072 * 1024;           // w_out^T  [1024][1024]
  unsigned short* Qb  = Wt2 + (size_t)1024 * 1024;           // [BH][T][64]
  unsigned short* Kb  = Qb  + (size_t)8388608;               // [BH][T][64]
  unsigned short* Vtb = Kb  + (size_t)8388608;               // [BH][64][T] (written by gemm_qkv)
  unsigned short* AO  = Vtb + (size_t)8388608;               // [M][1024] bf16

  prep      <<<dim3(12288), 256, 0, stream>>>(x, w_qkv, w_out, Xb, Wt1, Wt2);
  gemm_qkv  <<<dim3(24, 64), 256, 0, stream>>>(Xb, Wt1, Qb, Kb, Vtb);
  flash_attn<<<dim3(8, 64), 512, 0, stream>>>(Qb, Kb, Vtb, AO);
  gemm_out  <<<dim3(8, 64), 256, 0, stream>>>(AO, Wt2, b_out, out);
}

// Round 9
// 251.729 us; speedup vs baseline: 1.6595x; 1.0471x over previous
//
#include <hip/hip_runtime.h>

// Problem constants
#define NH 16
#define HD 64
#define CE 1024
#define TT 2048
#define BB 4
#define MM 8192   // B*T

using bf16x8 = __attribute__((ext_vector_type(8))) __bf16;
using f32x4  = __attribute__((ext_vector_type(4))) float;

__device__ __forceinline__ unsigned short f2bf(float f) {
  unsigned int u = __float_as_uint(f);
  u += 0x7fffu + ((u >> 16) & 1u);   // RNE
  return (unsigned short)(u >> 16);
}
__device__ __forceinline__ unsigned short f2bf_rtz(float f) {
  return (unsigned short)(__float_as_uint(f) >> 16);  // truncate: 1-op, used for P only
}

// async global->LDS, 16B per lane; LDS dst must be wave-uniform (HW adds lane*16)
__device__ __forceinline__ void async_cp16(const unsigned short* g, unsigned short* l) {
  __builtin_amdgcn_global_load_lds(
      (const __attribute__((address_space(1))) unsigned int*)g,
      (__attribute__((address_space(3))) unsigned int*)l, 16, 0, 0);
}

// ---------------- fused prep: convert_x + transpose(w_qkv) + transpose(w_out) ------------------
__global__ __launch_bounds__(256) void prep(const float* __restrict__ x,
                                            const float* __restrict__ w_qkv,
                                            const float* __restrict__ w_out,
                                            unsigned short* __restrict__ Xb,
                                            unsigned short* __restrict__ Wt1,
                                            unsigned short* __restrict__ Wt2) {
  __shared__ unsigned short tile[32][33];
  const int idx = blockIdx.x;
  if (idx < 8192) {
    const int i = (idx * 256 + threadIdx.x) * 4;
    const float4 v = *(const float4*)(x + i);
    ushort4 o;
    o.x = f2bf(v.x); o.y = f2bf(v.y); o.z = f2bf(v.z); o.w = f2bf(v.w);
    *(ushort4*)(Xb + i) = o;
    return;
  }
  const float* in;
  unsigned short* out;
  int rows, cols, bx, by;
  if (idx < 11264) {
    const int tc = idx - 8192;
    in = w_qkv; out = Wt1; rows = 1024; cols = 3072;
    bx = tc % 96; by = tc / 96;
  } else {
    const int tc = idx - 11264;
    in = w_out; out = Wt2; rows = 1024; cols = 1024;
    bx = tc & 31; by = tc >> 5;
  }
  const int c0 = bx * 32, r0 = by * 32;
  const int tx = threadIdx.x & 31, ty = threadIdx.x >> 5;  // ty 0..7
#pragma unroll
  for (int i = ty; i < 32; i += 8)
    tile[i][tx] = f2bf(in[(size_t)(r0 + i) * cols + c0 + tx]);
  __syncthreads();
#pragma unroll
  for (int i = ty; i < 32; i += 8)
    out[(size_t)(c0 + i) * rows + r0 + tx] = tile[tx][i];
}

// ---------------- GEMM core: T3 minimum-2-phase (double-buffered LDS, single barrier) ----------
// Per K-step: STAGE(t+1 -> other buffer) issued FIRST, then ds_read+MFMA on current buffer,
// then one __syncthreads (vmcnt(0)+lgkmcnt(0) drain). Loads for t+1 fly during t's 16 MFMAs
// instead of draining immediately (guide §5.5 T3 recipe; m230: 682 vs 655 TF at 2-phase).
// Race check: iter t reads buf[cur] (lgkm drained before barrier), stages buf[cur^1] (vmcnt
// drained at barrier); next iter reads buf[cur^1], overwrites buf[cur] whose reads completed.
__device__ __forceinline__ void gemm_core(const unsigned short* __restrict__ A,
                                          const unsigned short* __restrict__ BT,
                                          int m0, int n0, f32x4 (&acc)[4][4],
                                          unsigned short* As, unsigned short* Bs) {
  const int tid  = threadIdx.x;
  const int lane = tid & 63;
  const int wave = tid >> 6;
  const int quad = lane >> 4;
  const int l15  = lane & 15;
  const int wm = (wave & 1) * 64;
  const int wn = (wave >> 1) * 64;
  const int ldr = tid >> 2;         // 0..63
  const int ldc = (tid & 3) * 8;    // 0,8,16,24
  const unsigned short* Ap = A + (size_t)(m0 + ldr) * CE + ldc;
  const unsigned short* Bp = BT + (size_t)(n0 + ldr) * CE + ldc;
  const int wofs = wave * 512;
#define STAGE_K(buf, k0)                                                   \
  do {                                                                     \
    async_cp16(Ap + (k0), As + (buf) * 4096 + wofs);                       \
    async_cp16(Ap + (size_t)64 * CE + (k0), As + (buf) * 4096 + 2048 + wofs); \
    async_cp16(Bp + (k0), Bs + (buf) * 4096 + wofs);                       \
    async_cp16(Bp + (size_t)64 * CE + (k0), Bs + (buf) * 4096 + 2048 + wofs); \
  } while (0)
  STAGE_K(0, 0);
  __syncthreads();
  int cur = 0;
  for (int k0 = 0; k0 < CE; k0 += 32) {
    if (k0 + 32 < CE) STAGE_K(cur ^ 1, k0 + 32);   // issue next tile first; flies during MFMAs
    const unsigned short* Ab = As + cur * 4096;
    const unsigned short* Bb = Bs + cur * 4096;
    bf16x8 af[4], bfr[4];
#pragma unroll
    for (int i = 0; i < 4; i++) {
      af[i]  = *(const bf16x8*)&Ab[(wm + i * 16 + l15) * 32 + quad * 8];
      bfr[i] = *(const bf16x8*)&Bb[(wn + i * 16 + l15) * 32 + quad * 8];
    }
    __builtin_amdgcn_s_setprio(1);
#pragma unroll
    for (int mi = 0; mi < 4; mi++)
#pragma unroll
      for (int ni = 0; ni < 4; ni++)
        acc[mi][ni] = __builtin_amdgcn_mfma_f32_16x16x32_bf16(af[mi], bfr[ni], acc[mi][ni], 0, 0, 0);
    __builtin_amdgcn_s_setprio(0);
    __syncthreads();   // single barrier per K-step (drains vmcnt after the MFMAs, not before)
    cur ^= 1;
  }
#undef STAGE_K
}

// ---------------- GEMM 1: qkv = x @ w_qkv -> Q (scaled), K, and V written TRANSPOSED -----------
// Q pre-scaled by HD^-0.5 * log2(e): flash computes exp2(s) == exp(s / log2e) exactly.
// Blocks bx<8: Q, bx 8..15: K (direct [bh][t][d] writes). Blocks bx>=16: V — tile bounced
// through LDS in [d][t] layout and written to Vtb[bh][d][t] with coalesced u32 stores.
__global__ __launch_bounds__(256) void gemm_qkv(const unsigned short* __restrict__ A,
                                                const unsigned short* __restrict__ BT,
                                                unsigned short* __restrict__ Qb,
                                                unsigned short* __restrict__ Kb,
                                                unsigned short* __restrict__ Vtb) {
  __shared__ unsigned short pool[16384];  // As dbuf [2][4096] | Bs dbuf [2][4096]; V-epi aliases
  f32x4 acc[4][4] = {};
  const int m0 = blockIdx.y * 128, n0 = blockIdx.x * 128;
  gemm_core(A, BT, m0, n0, acc, pool, pool + 8192);
  const int tid = threadIdx.x, lane = tid & 63, wave = tid >> 6;
  const int quad = lane >> 4, l15 = lane & 15;
  const int wm = (wave & 1) * 64, wn = (wave >> 1) * 64;
  if (blockIdx.x >= 16) {
    // ---- V: transpose tile through LDS, write Vtb[bh][d][t] coalesced ----
    unsigned short* Vt = pool;                 // [128 d][66], aliases (safe after last barrier)
    const int h0 = 2 * (blockIdx.x - 16);      // first head of this 128-col tile
    const int bb = m0 >> 11;                   // batch (tile never crosses: 2048%128==0)
    const int t0g = m0 & 2047;
    const int l31 = tid & 31;
    const int rw  = tid >> 5;                  // 0..7
    unsigned int* __restrict__ VtU = (unsigned int*)Vtb;
#pragma unroll
    for (int hp = 0; hp < 2; hp++) {           // two passes of 64 t-rows
      __syncthreads();                         // prior pass reads (or gemm reads) done
      if ((wave & 1) == hp) {                  // waves whose wm == 64*hp own these t rows
#pragma unroll
        for (int mi = 0; mi < 4; mi++)
#pragma unroll
          for (int ni = 0; ni < 4; ni++) {
            const int row = wn + ni * 16 + l15;      // d-local 0..127
            const int col = mi * 16 + quad * 4;      // t-local 0..63 (+r)
#pragma unroll
            for (int r = 0; r < 4; r++)
              Vt[row * 66 + col + r] = f2bf(acc[mi][ni][r]);
          }
      }
      __syncthreads();
      // write out: 128 d-rows x 32 u32 (64 t), 8 rows in parallel
#pragma unroll
      for (int k = 0; k < 16; k++) {
        const int d = rw + 8 * k;              // 0..127
        const unsigned int v = *(const unsigned int*)&Vt[d * 66 + 2 * l31];
        const int hh = h0 + (d >> 6);
        VtU[((((size_t)(bb * 16 + hh) * 64 + (d & 63)) * TT + t0g + 64 * hp) >> 1) + l31] = v;
      }
    }
    return;
  }
  // ---- Q / K: direct scatter (coalesced over l15 -> d) ----
  const float QSCALE = 0.125f * 1.44269504088896340736f;
#pragma unroll
  for (int mi = 0; mi < 4; mi++) {
#pragma unroll
    for (int ni = 0; ni < 4; ni++) {
      const int n = n0 + wn + ni * 16 + l15;
      const int s = n >> 10;           // 0=q 1=k
      const int h = (n >> 6) & 15;
      const int d = n & 63;
#pragma unroll
      for (int r = 0; r < 4; r++) {
        const int m = m0 + wm + mi * 16 + quad * 4 + r;
        const int b = m >> 11;         // /2048
        const int t = m & 2047;
        const int bh = (b << 4) + h;
        const float v = acc[mi][ni][r];
        if (s == 0) Qb[((size_t)bh * TT + t) * HD + d] = f2bf(v * QSCALE);
        else        Kb[((size_t)bh * TT + t) * HD + d] = f2bf(v);
      }
    }
  }
}

// ---------------- GEMM 2: out = AO @ w_out + b_out (fp32 out) ----------------
__global__ __launch_bounds__(256) void gemm_out(const unsigned short* __restrict__ A,
                                                const unsigned short* __restrict__ BT,
                                                const float* __restrict__ bias,
                                                float* __restrict__ out) {
  __shared__ unsigned short pool[16384];
  f32x4 acc[4][4] = {};
  const int m0 = blockIdx.y * 128, n0 = blockIdx.x * 128;
  gemm_core(A, BT, m0, n0, acc, pool, pool + 8192);
  const int tid = threadIdx.x, lane = tid & 63, wave = tid >> 6;
  const int quad = lane >> 4, l15 = lane & 15;
  const int wm = (wave & 1) * 64, wn = (wave >> 1) * 64;
#pragma unroll
  for (int mi = 0; mi < 4; mi++) {
#pragma unroll
    for (int ni = 0; ni < 4; ni++) {
      const int n = n0 + wn + ni * 16 + l15;
      const float bv = bias[n];
#pragma unroll
      for (int r = 0; r < 4; r++) {
        const int m = m0 + wm + mi * 16 + quad * 4 + r;
        out[(size_t)m * CE + n] = acc[mi][ni][r] + bv;
      }
    }
  }
}

// ---------------- causal flash attention: round-4 verified kernel + vb hoist -------------------
// 512 thr / 8 waves; wave owns 16 Q rows. KV tile 64 staged once per block, shared by 8 waves.
// One-iteration-ahead register prefetch issued BEFORE the barrier. T1 XCD-chunked swizzle
// (verified: FETCH 152 -> 24.6 MB). T5 setprio. Block pairs q-tiles qx and 15-qx: 34 iters
// every block. Only change vs R4: V-fragment ds_reads hoisted above the exp2 chain (independent
// of P; their LDS-pipe time overlaps the VALU chain).
__global__ __launch_bounds__(512) void flash_attn(const unsigned short* __restrict__ Q,
                                                  const unsigned short* __restrict__ Kg,
                                                  const unsigned short* __restrict__ Vt,
                                                  unsigned short* __restrict__ AO) {
  __shared__ unsigned short Ks[64][72];     // [kv][d]
  __shared__ unsigned short Vs[64][72];     // [d][kv]
  __shared__ unsigned short Ps[8][16][72];  // per-wave P, [qrow 0..15][kv]
  const int flat = blockIdx.x + 8 * blockIdx.y;        // 0..511, hw dispatch order
  const int wu   = (flat & 7) * 64 + (flat >> 3);      // bijective remap
  const int qx   = wu & 7;                             // q-tile index 0..7
  const int bh   = wu >> 3;                            // head 0..63 (8 consecutive heads/XCD)
  const int tid = threadIdx.x, w = tid >> 6, lane = tid & 63;
  const int quad = lane >> 4, l15 = lane & 15;
  const int b = bh >> 4, h = bh & 15;
  const unsigned short* Kbase = Kg + (size_t)bh * TT * HD;
  const unsigned short* Vbase = Vt + (size_t)bh * HD * TT;
  const int srow = tid >> 3;        // 0..63
  const int scol = (tid & 7) * 8;   // 0..56 (x2B = 16B chunks)
  const bf16x8 ones = {1, 1, 1, 1, 1, 1, 1, 1};

  for (int ph = 0; ph < 2; ph++) {
    const int pt = ph ? (15 - qx) : qx;
    const int q0 = pt * 128;
    const int n_it = 2 * pt + 2;
    const int rbase = q0 + w * 16;    // this wave's first Q row
    bf16x8 qf[2];
    {
      const unsigned short* Qp =
          Q + ((size_t)bh * TT + rbase + l15) * HD + quad * 8;
      qf[0] = *(const bf16x8*)Qp;
      qf[1] = *(const bf16x8*)(Qp + 32);
    }
    f32x4 o[4] = {};
    f32x4 l_acc = {};
    uint4 kreg, vreg;
    {
      kreg = *(const uint4*)(Kbase + (size_t)srow * HD + scol);
      vreg = *(const uint4*)(Vbase + (size_t)srow * TT + scol);
    }
    for (int it = 0; it < n_it; it++) {
      const int kv0 = it * 64;
      *(uint4*)&Ks[srow][scol] = kreg;
      *(uint4*)&Vs[srow][scol] = vreg;
      {
        const int itn = (it + 1 < n_it) ? it + 1 : it;
        const int kvn = itn * 64;
        kreg = *(const uint4*)(Kbase + (size_t)(kvn + srow) * HD + scol);
        vreg = *(const uint4*)(Vbase + (size_t)srow * TT + kvn + scol);
      }
      __syncthreads();
      if (kv0 <= rbase + 15) {
        bf16x8 kb[4][2];
#pragma unroll
        for (int ni = 0; ni < 4; ni++) {
          kb[ni][0] = *(const bf16x8*)&Ks[ni * 16 + l15][quad * 8];
          kb[ni][1] = *(const bf16x8*)&Ks[ni * 16 + l15][32 + quad * 8];
        }
        f32x4 s[4];
        __builtin_amdgcn_s_setprio(1);
#pragma unroll
        for (int ni = 0; ni < 4; ni++) {
          f32x4 z = {};
          z = __builtin_amdgcn_mfma_f32_16x16x32_bf16(qf[0], kb[ni][0], z, 0, 0, 0);
          z = __builtin_amdgcn_mfma_f32_16x16x32_bf16(qf[1], kb[ni][1], z, 0, 0, 0);
          s[ni] = z;
        }
        __builtin_amdgcn_s_setprio(0);
        // V fragments hoisted: independent of P, overlap the exp2 chain below
        bf16x8 vb[4][2];
#pragma unroll
        for (int nd = 0; nd < 4; nd++) {
          vb[nd][0] = *(const bf16x8*)&Vs[nd * 16 + l15][quad * 8];
          vb[nd][1] = *(const bf16x8*)&Vs[nd * 16 + l15][32 + quad * 8];
        }
        if (kv0 + 63 > rbase) {
#pragma unroll
          for (int ni = 0; ni < 4; ni++) {
            const int col_g = kv0 + ni * 16 + l15;
#pragma unroll
            for (int r = 0; r < 4; r++) {
              const int row_g = rbase + quad * 4 + r;
              const float sv = (col_g <= row_g) ? s[ni][r] : -1e30f;
              Ps[w][quad * 4 + r][ni * 16 + l15] = f2bf_rtz(exp2f(sv));
            }
          }
        } else {
#pragma unroll
          for (int ni = 0; ni < 4; ni++)
#pragma unroll
            for (int r = 0; r < 4; r++)
              Ps[w][quad * 4 + r][ni * 16 + l15] = f2bf_rtz(exp2f(s[ni][r]));
        }
        bf16x8 pa[2];
        pa[0] = *(const bf16x8*)&Ps[w][l15][quad * 8];
        pa[1] = *(const bf16x8*)&Ps[w][l15][32 + quad * 8];
        __builtin_amdgcn_s_setprio(1);
        l_acc = __builtin_amdgcn_mfma_f32_16x16x32_bf16(pa[0], ones, l_acc, 0, 0, 0);
        l_acc = __builtin_amdgcn_mfma_f32_16x16x32_bf16(pa[1], ones, l_acc, 0, 0, 0);
#pragma unroll
        for (int nd = 0; nd < 4; nd++) {
          o[nd] = __builtin_amdgcn_mfma_f32_16x16x32_bf16(pa[0], vb[nd][0], o[nd], 0, 0, 0);
          o[nd] = __builtin_amdgcn_mfma_f32_16x16x32_bf16(pa[1], vb[nd][1], o[nd], 0, 0, 0);
        }
        __builtin_amdgcn_s_setprio(0);
      }
      __syncthreads();
    }
    {
      float rin[4];
#pragma unroll
      for (int r = 0; r < 4; r++) rin[r] = __builtin_amdgcn_rcpf(l_acc[r]);
#pragma unroll
      for (int nd = 0; nd < 4; nd++)
#pragma unroll
        for (int r = 0; r < 4; r++) {
          const int row_g = rbase + quad * 4 + r;
          const size_t mg = (size_t)b * TT + row_g;
          AO[mg * CE + h * 64 + nd * 16 + l15] = f2bf(o[nd][r] * rin[r]);
        }
    }
  }
}

extern "C" void kernel_launch(void* const* d_in, const int* in_sizes, int n_in,
                              void* d_out, int out_size, void* d_ws, size_t ws_size,
                              hipStream_t stream) {
  const float* x     = (const float*)d_in[0];  // [4,2048,1024] f32
  const float* w_qkv = (const float*)d_in[1];  // [1024,3072] f32
  const float* w_out = (const float*)d_in[2];  // [1024,1024] f32
  const float* b_out = (const float*)d_in[3];  // [1024] f32
  float* out = (float*)d_out;                  // [4,2048,1024] f32

  unsigned short* ws  = (unsigned short*)d_ws;
  unsigned short* Xb  = ws;                                  // x bf16 [8192][1024]
  unsigned short* Wt1 = Xb  + (size_t)MM * CE;               // w_qkv^T  [3072][1024]
  unsigned short* Wt2 = Wt1 + (size_t)3072 * 1024;           // w_out^T  [1024][1024]
  unsigned short* Qb  = Wt2 + (size_t)1024 * 1024;           // [BH][T][64]
  unsigned short* Kb  = Qb  + (size_t)8388608;               // [BH][T][64]
  unsigned short* Vtb = Kb  + (size_t)8388608;               // [BH][64][T] (written by gemm_qkv)
  unsigned short* AO  = Vtb + (size_t)8388608;               // [M][1024] bf16

  prep      <<<dim3(12288), 256, 0, stream>>>(x, w_qkv, w_out, Xb, Wt1, Wt2);
  gemm_qkv  <<<dim3(24, 64), 256, 0, stream>>>(Xb, Wt1, Qb, Kb, Vtb);
  flash_attn<<<dim3(8, 64), 512, 0, stream>>>(Qb, Kb, Vtb, AO);
  gemm_out  <<<dim3(8, 64), 256, 0, stream>>>(AO, Wt2, b_out, out);
}

// Round 10
// 249.982 us; speedup vs baseline: 1.6711x; 1.0070x over previous
//
#include <hip/hip_runtime.h>

// Problem constants
#define NH 16
#define HD 64
#define CE 1024
#define TT 2048
#define BB 4
#define MM 8192   // B*T

using bf16x8 = __attribute__((ext_vector_type(8))) __bf16;
using f32x4  = __attribute__((ext_vector_type(4))) float;

__device__ __forceinline__ unsigned short f2bf(float f) {
  unsigned int u = __float_as_uint(f);
  u += 0x7fffu + ((u >> 16) & 1u);   // RNE
  return (unsigned short)(u >> 16);
}
__device__ __forceinline__ unsigned short f2bf_rtz(float f) {
  return (unsigned short)(__float_as_uint(f) >> 16);  // truncate: 1-op, used for P only
}

// async global->LDS, 16B per lane; LDS dst must be wave-uniform (HW adds lane*16)
__device__ __forceinline__ void async_cp16(const unsigned short* g, unsigned short* l) {
  __builtin_amdgcn_global_load_lds(
      (const __attribute__((address_space(1))) unsigned int*)g,
      (__attribute__((address_space(3))) unsigned int*)l, 16, 0, 0);
}

// ---------------- fused prep: convert_x + transpose(w_qkv) + transpose(w_out) ------------------
__global__ __launch_bounds__(256) void prep(const float* __restrict__ x,
                                            const float* __restrict__ w_qkv,
                                            const float* __restrict__ w_out,
                                            unsigned short* __restrict__ Xb,
                                            unsigned short* __restrict__ Wt1,
                                            unsigned short* __restrict__ Wt2) {
  __shared__ unsigned short tile[32][33];
  const int idx = blockIdx.x;
  if (idx < 8192) {
    const int i = (idx * 256 + threadIdx.x) * 4;
    const float4 v = *(const float4*)(x + i);
    ushort4 o;
    o.x = f2bf(v.x); o.y = f2bf(v.y); o.z = f2bf(v.z); o.w = f2bf(v.w);
    *(ushort4*)(Xb + i) = o;
    return;
  }
  const float* in;
  unsigned short* out;
  int rows, cols, bx, by;
  if (idx < 11264) {
    const int tc = idx - 8192;
    in = w_qkv; out = Wt1; rows = 1024; cols = 3072;
    bx = tc % 96; by = tc / 96;
  } else {
    const int tc = idx - 11264;
    in = w_out; out = Wt2; rows = 1024; cols = 1024;
    bx = tc & 31; by = tc >> 5;
  }
  const int c0 = bx * 32, r0 = by * 32;
  const int tx = threadIdx.x & 31, ty = threadIdx.x >> 5;  // ty 0..7
#pragma unroll
  for (int i = ty; i < 32; i += 8)
    tile[i][tx] = f2bf(in[(size_t)(r0 + i) * cols + c0 + tx]);
  __syncthreads();
#pragma unroll
  for (int i = ty; i < 32; i += 8)
    out[(size_t)(c0 + i) * rows + r0 + tx] = tile[tx][i];
}

// ---------------- GEMM core: T3 minimum-2-phase (double-buffered LDS, single barrier) ----------
// Per K-step: STAGE(t+1 -> other buffer) issued FIRST, then ds_read+MFMA on current buffer,
// then one __syncthreads (vmcnt(0)+lgkmcnt(0) drain). Verified R9: gemm_qkv 81 -> <83 top-5 exit.
__device__ __forceinline__ void gemm_core(const unsigned short* __restrict__ A,
                                          const unsigned short* __restrict__ BT,
                                          int m0, int n0, f32x4 (&acc)[4][4],
                                          unsigned short* As, unsigned short* Bs) {
  const int tid  = threadIdx.x;
  const int lane = tid & 63;
  const int wave = tid >> 6;
  const int quad = lane >> 4;
  const int l15  = lane & 15;
  const int wm = (wave & 1) * 64;
  const int wn = (wave >> 1) * 64;
  const int ldr = tid >> 2;         // 0..63
  const int ldc = (tid & 3) * 8;    // 0,8,16,24
  const unsigned short* Ap = A + (size_t)(m0 + ldr) * CE + ldc;
  const unsigned short* Bp = BT + (size_t)(n0 + ldr) * CE + ldc;
  const int wofs = wave * 512;
#define STAGE_K(buf, k0)                                                   \
  do {                                                                     \
    async_cp16(Ap + (k0), As + (buf) * 4096 + wofs);                       \
    async_cp16(Ap + (size_t)64 * CE + (k0), As + (buf) * 4096 + 2048 + wofs); \
    async_cp16(Bp + (k0), Bs + (buf) * 4096 + wofs);                       \
    async_cp16(Bp + (size_t)64 * CE + (k0), Bs + (buf) * 4096 + 2048 + wofs); \
  } while (0)
  STAGE_K(0, 0);
  __syncthreads();
  int cur = 0;
  for (int k0 = 0; k0 < CE; k0 += 32) {
    if (k0 + 32 < CE) STAGE_K(cur ^ 1, k0 + 32);   // issue next tile first; flies during MFMAs
    const unsigned short* Ab = As + cur * 4096;
    const unsigned short* Bb = Bs + cur * 4096;
    bf16x8 af[4], bfr[4];
#pragma unroll
    for (int i = 0; i < 4; i++) {
      af[i]  = *(const bf16x8*)&Ab[(wm + i * 16 + l15) * 32 + quad * 8];
      bfr[i] = *(const bf16x8*)&Bb[(wn + i * 16 + l15) * 32 + quad * 8];
    }
    __builtin_amdgcn_s_setprio(1);
#pragma unroll
    for (int mi = 0; mi < 4; mi++)
#pragma unroll
      for (int ni = 0; ni < 4; ni++)
        acc[mi][ni] = __builtin_amdgcn_mfma_f32_16x16x32_bf16(af[mi], bfr[ni], acc[mi][ni], 0, 0, 0);
    __builtin_amdgcn_s_setprio(0);
    __syncthreads();   // single barrier per K-step (drains vmcnt after the MFMAs, not before)
    cur ^= 1;
  }
#undef STAGE_K
}

// ---------------- GEMM 1: qkv = x @ w_qkv -> Q (scaled), K, and V written TRANSPOSED -----------
// Q pre-scaled by HD^-0.5 * log2(e): flash computes exp2(s) == exp(s / log2e) exactly.
// Blocks bx<8: Q, bx 8..15: K (direct [bh][t][d] writes). Blocks bx>=16: V — tile bounced
// through LDS in [d][t] layout and written to Vtb[bh][d][t] with coalesced u32 stores.
__global__ __launch_bounds__(256) void gemm_qkv(const unsigned short* __restrict__ A,
                                                const unsigned short* __restrict__ BT,
                                                unsigned short* __restrict__ Qb,
                                                unsigned short* __restrict__ Kb,
                                                unsigned short* __restrict__ Vtb) {
  __shared__ unsigned short pool[16384];  // As dbuf [2][4096] | Bs dbuf [2][4096]; V-epi aliases
  f32x4 acc[4][4] = {};
  const int m0 = blockIdx.y * 128, n0 = blockIdx.x * 128;
  gemm_core(A, BT, m0, n0, acc, pool, pool + 8192);
  const int tid = threadIdx.x, lane = tid & 63, wave = tid >> 6;
  const int quad = lane >> 4, l15 = lane & 15;
  const int wm = (wave & 1) * 64, wn = (wave >> 1) * 64;
  if (blockIdx.x >= 16) {
    // ---- V: transpose tile through LDS, write Vtb[bh][d][t] coalesced ----
    unsigned short* Vt = pool;                 // [128 d][66], aliases (safe after last barrier)
    const int h0 = 2 * (blockIdx.x - 16);      // first head of this 128-col tile
    const int bb = m0 >> 11;                   // batch (tile never crosses: 2048%128==0)
    const int t0g = m0 & 2047;
    const int l31 = tid & 31;
    const int rw  = tid >> 5;                  // 0..7
    unsigned int* __restrict__ VtU = (unsigned int*)Vtb;
#pragma unroll
    for (int hp = 0; hp < 2; hp++) {           // two passes of 64 t-rows
      __syncthreads();                         // prior pass reads (or gemm reads) done
      if ((wave & 1) == hp) {                  // waves whose wm == 64*hp own these t rows
#pragma unroll
        for (int mi = 0; mi < 4; mi++)
#pragma unroll
          for (int ni = 0; ni < 4; ni++) {
            const int row = wn + ni * 16 + l15;      // d-local 0..127
            const int col = mi * 16 + quad * 4;      // t-local 0..63 (+r)
#pragma unroll
            for (int r = 0; r < 4; r++)
              Vt[row * 66 + col + r] = f2bf(acc[mi][ni][r]);
          }
      }
      __syncthreads();
      // write out: 128 d-rows x 32 u32 (64 t), 8 rows in parallel
#pragma unroll
      for (int k = 0; k < 16; k++) {
        const int d = rw + 8 * k;              // 0..127
        const unsigned int v = *(const unsigned int*)&Vt[d * 66 + 2 * l31];
        const int hh = h0 + (d >> 6);
        VtU[((((size_t)(bb * 16 + hh) * 64 + (d & 63)) * TT + t0g + 64 * hp) >> 1) + l31] = v;
      }
    }
    return;
  }
  // ---- Q / K: direct scatter (coalesced over l15 -> d) ----
  const float QSCALE = 0.125f * 1.44269504088896340736f;
#pragma unroll
  for (int mi = 0; mi < 4; mi++) {
#pragma unroll
    for (int ni = 0; ni < 4; ni++) {
      const int n = n0 + wn + ni * 16 + l15;
      const int s = n >> 10;           // 0=q 1=k
      const int h = (n >> 6) & 15;
      const int d = n & 63;
#pragma unroll
      for (int r = 0; r < 4; r++) {
        const int m = m0 + wm + mi * 16 + quad * 4 + r;
        const int b = m >> 11;         // /2048
        const int t = m & 2047;
        const int bh = (b << 4) + h;
        const float v = acc[mi][ni][r];
        if (s == 0) Qb[((size_t)bh * TT + t) * HD + d] = f2bf(v * QSCALE);
        else        Kb[((size_t)bh * TT + t) * HD + d] = f2bf(v);
      }
    }
  }
}

// ---------------- GEMM 2: out = AO @ w_out + b_out (fp32 out) ----------------
__global__ __launch_bounds__(256) void gemm_out(const unsigned short* __restrict__ A,
                                                const unsigned short* __restrict__ BT,
                                                const float* __restrict__ bias,
                                                float* __restrict__ out) {
  __shared__ unsigned short pool[16384];
  f32x4 acc[4][4] = {};
  const int m0 = blockIdx.y * 128, n0 = blockIdx.x * 128;
  gemm_core(A, BT, m0, n0, acc, pool, pool + 8192);
  const int tid = threadIdx.x, lane = tid & 63, wave = tid >> 6;
  const int quad = lane >> 4, l15 = lane & 15;
  const int wm = (wave & 1) * 64, wn = (wave >> 1) * 64;
#pragma unroll
  for (int mi = 0; mi < 4; mi++) {
#pragma unroll
    for (int ni = 0; ni < 4; ni++) {
      const int n = n0 + wn + ni * 16 + l15;
      const float bv = bias[n];
#pragma unroll
      for (int r = 0; r < 4; r++) {
        const int m = m0 + wm + mi * 16 + quad * 4 + r;
        out[(size_t)m * CE + n] = acc[mi][ni][r] + bv;
      }
    }
  }
}

// ---------------- causal flash attention: round-4/round-8 verified kernel, VERBATIM ------------
// 512 thr / 8 waves; wave owns 16 Q rows. KV tile 64 staged once per block, shared by 8 waves.
// One-iteration-ahead register prefetch issued BEFORE the barrier. T1 XCD-chunked swizzle
// (verified: FETCH 152 -> 24.6 MB). T5 setprio. Block pairs q-tiles qx and 15-qx: 34 iters
// every block. V-fragment reads stay AFTER the exp chain — hoisting them cost +6us (R9).
// This body has rejected 4 perturbations (R5/R6/R7/R9): do not touch.
__global__ __launch_bounds__(512) void flash_attn(const unsigned short* __restrict__ Q,
                                                  const unsigned short* __restrict__ Kg,
                                                  const unsigned short* __restrict__ Vt,
                                                  unsigned short* __restrict__ AO) {
  __shared__ unsigned short Ks[64][72];     // [kv][d]
  __shared__ unsigned short Vs[64][72];     // [d][kv]
  __shared__ unsigned short Ps[8][16][72];  // per-wave P, [qrow 0..15][kv]
  const int flat = blockIdx.x + 8 * blockIdx.y;        // 0..511, hw dispatch order
  const int wu   = (flat & 7) * 64 + (flat >> 3);      // bijective remap
  const int qx   = wu & 7;                             // q-tile index 0..7
  const int bh   = wu >> 3;                            // head 0..63 (8 consecutive heads/XCD)
  const int tid = threadIdx.x, w = tid >> 6, lane = tid & 63;
  const int quad = lane >> 4, l15 = lane & 15;
  const int b = bh >> 4, h = bh & 15;
  const unsigned short* Kbase = Kg + (size_t)bh * TT * HD;
  const unsigned short* Vbase = Vt + (size_t)bh * HD * TT;
  const int srow = tid >> 3;        // 0..63
  const int scol = (tid & 7) * 8;   // 0..56 (x2B = 16B chunks)
  const bf16x8 ones = {1, 1, 1, 1, 1, 1, 1, 1};

  for (int ph = 0; ph < 2; ph++) {
    const int pt = ph ? (15 - qx) : qx;
    const int q0 = pt * 128;
    const int n_it = 2 * pt + 2;
    const int rbase = q0 + w * 16;    // this wave's first Q row
    bf16x8 qf[2];
    {
      const unsigned short* Qp =
          Q + ((size_t)bh * TT + rbase + l15) * HD + quad * 8;
      qf[0] = *(const bf16x8*)Qp;
      qf[1] = *(const bf16x8*)(Qp + 32);
    }
    f32x4 o[4] = {};
    f32x4 l_acc = {};
    uint4 kreg, vreg;
    {
      kreg = *(const uint4*)(Kbase + (size_t)srow * HD + scol);
      vreg = *(const uint4*)(Vbase + (size_t)srow * TT + scol);
    }
    for (int it = 0; it < n_it; it++) {
      const int kv0 = it * 64;
      *(uint4*)&Ks[srow][scol] = kreg;
      *(uint4*)&Vs[srow][scol] = vreg;
      {
        const int itn = (it + 1 < n_it) ? it + 1 : it;
        const int kvn = itn * 64;
        kreg = *(const uint4*)(Kbase + (size_t)(kvn + srow) * HD + scol);
        vreg = *(const uint4*)(Vbase + (size_t)srow * TT + kvn + scol);
      }
      __syncthreads();
      if (kv0 <= rbase + 15) {
        bf16x8 kb[4][2];
#pragma unroll
        for (int ni = 0; ni < 4; ni++) {
          kb[ni][0] = *(const bf16x8*)&Ks[ni * 16 + l15][quad * 8];
          kb[ni][1] = *(const bf16x8*)&Ks[ni * 16 + l15][32 + quad * 8];
        }
        f32x4 s[4];
        __builtin_amdgcn_s_setprio(1);
#pragma unroll
        for (int ni = 0; ni < 4; ni++) {
          f32x4 z = {};
          z = __builtin_amdgcn_mfma_f32_16x16x32_bf16(qf[0], kb[ni][0], z, 0, 0, 0);
          z = __builtin_amdgcn_mfma_f32_16x16x32_bf16(qf[1], kb[ni][1], z, 0, 0, 0);
          s[ni] = z;
        }
        __builtin_amdgcn_s_setprio(0);
        if (kv0 + 63 > rbase) {
#pragma unroll
          for (int ni = 0; ni < 4; ni++) {
            const int col_g = kv0 + ni * 16 + l15;
#pragma unroll
            for (int r = 0; r < 4; r++) {
              const int row_g = rbase + quad * 4 + r;
              const float sv = (col_g <= row_g) ? s[ni][r] : -1e30f;
              Ps[w][quad * 4 + r][ni * 16 + l15] = f2bf_rtz(exp2f(sv));
            }
          }
        } else {
#pragma unroll
          for (int ni = 0; ni < 4; ni++)
#pragma unroll
            for (int r = 0; r < 4; r++)
              Ps[w][quad * 4 + r][ni * 16 + l15] = f2bf_rtz(exp2f(s[ni][r]));
        }
        bf16x8 pa[2];
        pa[0] = *(const bf16x8*)&Ps[w][l15][quad * 8];
        pa[1] = *(const bf16x8*)&Ps[w][l15][32 + quad * 8];
        bf16x8 vb[4][2];
#pragma unroll
        for (int nd = 0; nd < 4; nd++) {
          vb[nd][0] = *(const bf16x8*)&Vs[nd * 16 + l15][quad * 8];
          vb[nd][1] = *(const bf16x8*)&Vs[nd * 16 + l15][32 + quad * 8];
        }
        __builtin_amdgcn_s_setprio(1);
        l_acc = __builtin_amdgcn_mfma_f32_16x16x32_bf16(pa[0], ones, l_acc, 0, 0, 0);
        l_acc = __builtin_amdgcn_mfma_f32_16x16x32_bf16(pa[1], ones, l_acc, 0, 0, 0);
#pragma unroll
        for (int nd = 0; nd < 4; nd++) {
          o[nd] = __builtin_amdgcn_mfma_f32_16x16x32_bf16(pa[0], vb[nd][0], o[nd], 0, 0, 0);
          o[nd] = __builtin_amdgcn_mfma_f32_16x16x32_bf16(pa[1], vb[nd][1], o[nd], 0, 0, 0);
        }
        __builtin_amdgcn_s_setprio(0);
      }
      __syncthreads();
    }
    {
      float rin[4];
#pragma unroll
      for (int r = 0; r < 4; r++) rin[r] = __builtin_amdgcn_rcpf(l_acc[r]);
#pragma unroll
      for (int nd = 0; nd < 4; nd++)
#pragma unroll
        for (int r = 0; r < 4; r++) {
          const int row_g = rbase + quad * 4 + r;
          const size_t mg = (size_t)b * TT + row_g;
          AO[mg * CE + h * 64 + nd * 16 + l15] = f2bf(o[nd][r] * rin[r]);
        }
    }
  }
}

extern "C" void kernel_launch(void* const* d_in, const int* in_sizes, int n_in,
                              void* d_out, int out_size, void* d_ws, size_t ws_size,
                              hipStream_t stream) {
  const float* x     = (const float*)d_in[0];  // [4,2048,1024] f32
  const float* w_qkv = (const float*)d_in[1];  // [1024,3072] f32
  const float* w_out = (const float*)d_in[2];  // [1024,1024] f32
  const float* b_out = (const float*)d_in[3];  // [1024] f32
  float* out = (float*)d_out;                  // [4,2048,1024] f32

  unsigned short* ws  = (unsigned short*)d_ws;
  unsigned short* Xb  = ws;                                  // x bf16 [8192][1024]
  unsigned short* Wt1 = Xb  + (size_t)MM * CE;               // w_qkv^T  [3072][1024]
  unsigned short* Wt2 = Wt1 + (size_t)3072 * 1024;           // w_out^T  [1024][1024]
  unsigned short* Qb  = Wt2 + (size_t)1024 * 1024;           // [BH][T][64]
  unsigned short* Kb  = Qb  + (size_t)8388608;               // [BH][T][64]
  unsigned short* Vtb = Kb  + (size_t)8388608;               // [BH][64][T] (written by gemm_qkv)
  unsigned short* AO  = Vtb + (size_t)8388608;               // [M][1024] bf16

  prep      <<<dim3(12288), 256, 0, stream>>>(x, w_qkv, w_out, Xb, Wt1, Wt2);
  gemm_qkv  <<<dim3(24, 64), 256, 0, stream>>>(Xb, Wt1, Qb, Kb, Vtb);
  flash_attn<<<dim3(8, 64), 512, 0, stream>>>(Qb, Kb, Vtb, AO);
  gemm_out  <<<dim3(8, 64), 256, 0, stream>>>(AO, Wt2, b_out, out);
}